// Round 1
// baseline (5363.674 us; speedup 1.0000x reference)
//
#include <hip/hip_runtime.h>
#include <cstddef>

#define NN 100000
#define NE 1600000
#define KIN 512
#define FD 128
#define NC 10

// ---------------- degree kernels ----------------
__global__ void k_init_deg(float* __restrict__ degm, float* __restrict__ degh, int n) {
    int i = blockIdx.x * 256 + threadIdx.x;
    if (i < n) { degm[i] = 1.0f; degh[i] = 1.0f; }
}

__global__ void k_hist(const int* __restrict__ dst, float* __restrict__ deg, int E) {
    int e = blockIdx.x * 256 + threadIdx.x;
    if (e < E) atomicAdd(&deg[dst[e]], 1.0f);
}

__global__ void k_finalize(const float* __restrict__ deg, float* __restrict__ dis,
                           float* __restrict__ inv, int n) {
    int i = blockIdx.x * 256 + threadIdx.x;
    if (i < n) {
        float d = deg[i];
        dis[i] = rsqrtf(d);
        inv[i] = 1.0f / d;
    }
}

// ---------------- tiled fp32 GEMM: C[M x 128] = op(A[M x K]) @ B[K x 128] ----------------
// block 256 threads, tile 64 rows x 128 cols, K-tile 16, micro-tile 8x4
__global__ __launch_bounds__(256) void k_gemm(
    const float* __restrict__ A, const float* __restrict__ B,
    const float* __restrict__ bias, float* __restrict__ C,
    int M, int K, int relu_a, int relu_out) {
    __shared__ __align__(16) float As[16][68];   // transposed, padded
    __shared__ __align__(16) float Bs[16][128];

    const int tid = threadIdx.x;
    const int row0 = blockIdx.x * 64;
    const int tx = tid & 31;    // col group: 4 cols each
    const int ty = tid >> 5;    // row group: 8 rows each

    float acc[8][4];
#pragma unroll
    for (int r = 0; r < 8; ++r)
#pragma unroll
        for (int c = 0; c < 4; ++c) acc[r][c] = 0.0f;

    const int lrow = tid >> 2;        // 0..63
    const int lk = (tid & 3) * 4;     // 0,4,8,12

    for (int k0 = 0; k0 < K; k0 += 16) {
        // stage A tile (transposed into LDS)
        float4 av = make_float4(0.f, 0.f, 0.f, 0.f);
        int ar = row0 + lrow;
        if (ar < M) av = *(const float4*)(A + (size_t)ar * K + k0 + lk);
        if (relu_a) {
            av.x = fmaxf(av.x, 0.f); av.y = fmaxf(av.y, 0.f);
            av.z = fmaxf(av.z, 0.f); av.w = fmaxf(av.w, 0.f);
        }
        As[lk + 0][lrow] = av.x;
        As[lk + 1][lrow] = av.y;
        As[lk + 2][lrow] = av.z;
        As[lk + 3][lrow] = av.w;
        // stage B tile
#pragma unroll
        for (int i = 0; i < 2; ++i) {
            int f4 = tid + i * 256;           // 0..511
            int bk = f4 >> 5;                 // 0..15
            int bc = (f4 & 31) * 4;           // 0..124
            *(float4*)&Bs[bk][bc] = *(const float4*)(B + (size_t)(k0 + bk) * 128 + bc);
        }
        __syncthreads();
#pragma unroll
        for (int k = 0; k < 16; ++k) {
            float4 a0 = *(const float4*)&As[k][ty * 8];
            float4 a1 = *(const float4*)&As[k][ty * 8 + 4];
            float4 bv = *(const float4*)&Bs[k][tx * 4];
            float a[8] = {a0.x, a0.y, a0.z, a0.w, a1.x, a1.y, a1.z, a1.w};
            float b[4] = {bv.x, bv.y, bv.z, bv.w};
#pragma unroll
            for (int r = 0; r < 8; ++r)
#pragma unroll
                for (int c = 0; c < 4; ++c)
                    acc[r][c] = fmaf(a[r], b[c], acc[r][c]);
        }
        __syncthreads();
    }

    float4 bv = make_float4(0.f, 0.f, 0.f, 0.f);
    if (bias) bv = *(const float4*)(bias + tx * 4);
#pragma unroll
    for (int r = 0; r < 8; ++r) {
        int rr = row0 + ty * 8 + r;
        if (rr < M) {
            float4 o;
            o.x = acc[r][0] + bv.x; o.y = acc[r][1] + bv.y;
            o.z = acc[r][2] + bv.z; o.w = acc[r][3] + bv.w;
            if (relu_out) {
                o.x = fmaxf(o.x, 0.f); o.y = fmaxf(o.y, 0.f);
                o.z = fmaxf(o.z, 0.f); o.w = fmaxf(o.w, 0.f);
            }
            *(float4*)(C + (size_t)rr * 128 + tx * 4) = o;
        }
    }
}

// ---------------- small GEMM: C[M x 10] = op(A[M x 128]) @ W[128 x 10] ----------------
__global__ __launch_bounds__(256) void k_gemm10(
    const float* __restrict__ A, const float* __restrict__ W,
    float* __restrict__ C, int M, int relu_a) {
    __shared__ float Ws[128 * 10];
    int tid = threadIdx.x;
    for (int i = tid; i < 1280; i += 256) Ws[i] = W[i];
    __syncthreads();
    int row = blockIdx.x * 256 + tid;
    if (row >= M) return;
    float acc[10];
#pragma unroll
    for (int c = 0; c < 10; ++c) acc[c] = 0.0f;
    const float* a = A + (size_t)row * 128;
    for (int k = 0; k < 128; k += 4) {
        float4 av = *(const float4*)(a + k);
        if (relu_a) {
            av.x = fmaxf(av.x, 0.f); av.y = fmaxf(av.y, 0.f);
            av.z = fmaxf(av.z, 0.f); av.w = fmaxf(av.w, 0.f);
        }
        float vs[4] = {av.x, av.y, av.z, av.w};
#pragma unroll
        for (int j = 0; j < 4; ++j)
#pragma unroll
            for (int c = 0; c < 10; ++c)
                acc[c] = fmaf(vs[j], Ws[(k + j) * 10 + c], acc[c]);
    }
    float* o = C + (size_t)row * 10;
#pragma unroll
    for (int c = 0; c < 10; ++c) o[c] = acc[c];
}

// ---------------- GCN aggregation (F=128) ----------------
// init: out[n,:] = h[src_n,:]*inv[n] + b   (self-loop term + bias)
__global__ void k_agg_init(float* __restrict__ out, const float* __restrict__ h,
                           const int* __restrict__ permIdx, const float* __restrict__ inv,
                           const float* __restrict__ bias, int n) {
    int i4 = blockIdx.x * 256 + threadIdx.x;     // float4 index over n*32
    if (i4 >= n * 32) return;
    int node = i4 >> 5;
    int c4 = i4 & 31;
    int sn = permIdx ? permIdx[node] : node;
    float4 hv = ((const float4*)h)[(size_t)sn * 32 + c4];
    float4 bv = ((const float4*)bias)[c4];
    float s = inv[node];
    float4 o;
    o.x = fmaf(hv.x, s, bv.x); o.y = fmaf(hv.y, s, bv.y);
    o.z = fmaf(hv.z, s, bv.z); o.w = fmaf(hv.w, s, bv.w);
    ((float4*)out)[(size_t)node * 32 + c4] = o;
}

// scatter: out[dst,:] += h[src,:] * dis[src]*dis[dst]  -- 128 lanes per edge (wave-uniform e)
__global__ void k_agg_scatter(float* __restrict__ out, const float* __restrict__ h,
                              const int* __restrict__ permIdx,
                              const int* __restrict__ srcs, const int* __restrict__ dsts,
                              const float* __restrict__ dis, int E) {
    int gid = blockIdx.x * 256 + threadIdx.x;
    int e = gid >> 7;
    int f = gid & 127;
    if (e >= E) return;
    e = __builtin_amdgcn_readfirstlane(e);   // wave-uniform -> scalar loads
    int s = srcs[e];
    int d = dsts[e];
    float w = dis[s] * dis[d];
    if (permIdx) s = permIdx[s];
    float hv = h[(size_t)s * 128 + f];
    atomicAdd(out + (size_t)d * 128 + f, hv * w);
}

// ---------------- classifier aggregation (F=10, writes d_out stride 12) ----------------
__global__ void k_agg10_init(float* __restrict__ out, const float* __restrict__ hc,
                             const float* __restrict__ inv, const float* __restrict__ bc,
                             int n) {
    int gid = blockIdx.x * 256 + threadIdx.x;
    int node = gid >> 4;
    int c = gid & 15;
    if (node >= n || c >= 10) return;
    out[(size_t)node * 12 + c] = fmaf(hc[(size_t)node * 10 + c], inv[node], bc[c]);
}

__global__ void k_agg10_scatter(float* __restrict__ out, const float* __restrict__ hc,
                                const int* __restrict__ srcs, const int* __restrict__ dsts,
                                const float* __restrict__ dis, int E) {
    int gid = blockIdx.x * 256 + threadIdx.x;
    int e = gid >> 4;
    int f = gid & 15;
    if (e >= E || f >= 10) return;
    int s = srcs[e];
    int d = dsts[e];
    float w = dis[s] * dis[d];
    atomicAdd(out + (size_t)d * 12 + f, hc[(size_t)s * 10 + f] * w);
}

// ---------------- bilinear scores: sigmoid(sum_j v[n,j]*e2[n,j]) ----------------
__global__ void k_score(const float* __restrict__ v, const float* __restrict__ e2,
                        const float* __restrict__ e2b, float* __restrict__ out, int n) {
    int tid = threadIdx.x;
    int node = blockIdx.x * 4 + (tid >> 6);
    int lane = tid & 63;
    if (node >= n) return;
    const float* vp = v + (size_t)node * 128;
    const float* ap = e2 + (size_t)node * 128;
    const float* bp = e2b + (size_t)node * 128;
    float v0 = vp[lane], v1 = vp[lane + 64];
    float s1 = v0 * ap[lane] + v1 * ap[lane + 64];
    float s2 = v0 * bp[lane] + v1 * bp[lane + 64];
#pragma unroll
    for (int off = 32; off > 0; off >>= 1) {
        s1 += __shfl_xor(s1, off);
        s2 += __shfl_xor(s2, off);
    }
    if (lane == 0) {
        out[(size_t)node * 12 + 10] = 1.0f / (1.0f + __expf(-s1));
        out[(size_t)node * 12 + 11] = 1.0f / (1.0f + __expf(-s2));
    }
}

extern "C" void kernel_launch(void* const* d_in, const int* in_sizes, int n_in,
                              void* d_out, int out_size, void* d_ws, size_t ws_size,
                              hipStream_t stream) {
    const float* x   = (const float*)d_in[0];
    const int*   ei  = (const int*)d_in[1];
    const int*   eih = (const int*)d_in[2];
    const int*   perm = (const int*)d_in[4];
    const float* W1 = (const float*)d_in[5];
    const float* b1 = (const float*)d_in[6];
    const float* W2 = (const float*)d_in[7];
    const float* b2 = (const float*)d_in[8];
    const float* W3 = (const float*)d_in[9];
    const float* b3 = (const float*)d_in[10];
    const float* M1 = (const float*)d_in[11];
    const float* mb1 = (const float*)d_in[12];
    const float* M2 = (const float*)d_in[13];
    const float* mb2 = (const float*)d_in[14];
    const float* Wc = (const float*)d_in[15];
    const float* bc = (const float*)d_in[16];
    const float* Wd = (const float*)d_in[17];
    float* out = (float*)d_out;

    const int N = NN, E = NE;
    const int* src_m = ei;
    const int* dst_m = ei + E;
    const int* src_h = eih;
    const int* dst_h = eih + E;

    float* ws = (float*)d_ws;
    float* deg_m = ws;                 // N
    float* deg_h = deg_m + N;
    float* dis_m = deg_h + N;
    float* dis_h = dis_m + N;
    float* inv_m = dis_h + N;
    float* inv_h = inv_m + N;
    const size_t SLOT = (size_t)N * 128;
    float* sH = inv_h + N;
    float* sA = sH + SLOT;
    float* sB = sA + SLOT;
    float* sC = sB + SLOT;
    float* sE = sC + SLOT;
    float* sF = sE + SLOT;             // N*10

    const int gN = (N + 255) / 256;
    const int gE = (E + 255) / 256;
    const int gGemm = (N + 63) / 64;
    const int gInit = (N * 32 + 255) / 256;      // 12500
    const int gScat = (E * 128) / 256;           // 800000
    const int gI10 = (N * 16 + 255) / 256;
    const int gS10 = (E * 16) / 256;
    const int gScore = (N + 3) / 4;

    // degrees
    k_init_deg<<<gN, 256, 0, stream>>>(deg_m, deg_h, N);
    k_hist<<<gE, 256, 0, stream>>>(dst_m, deg_m, E);
    k_hist<<<gE, 256, 0, stream>>>(dst_h, deg_h, E);
    k_finalize<<<gN, 256, 0, stream>>>(deg_m, dis_m, inv_m, N);
    k_finalize<<<gN, 256, 0, stream>>>(deg_h, dis_h, inv_h, N);

    // h1 = x @ W1  (shared by both branches; bad branch uses perm indirection)
    k_gemm<<<gGemm, 256, 0, stream>>>(x, W1, nullptr, sH, N, KIN, 0, 0);

    // agg1 = gcn_agg(h1) -> sA ; agg1b = gcn_agg(h1[perm]) -> sB
    k_agg_init<<<gInit, 256, 0, stream>>>(sA, sH, nullptr, inv_m, b1, N);
    k_agg_scatter<<<gScat, 256, 0, stream>>>(sA, sH, nullptr, src_m, dst_m, dis_m, E);
    k_agg_init<<<gInit, 256, 0, stream>>>(sB, sH, perm, inv_m, b1, N);
    k_agg_scatter<<<gScat, 256, 0, stream>>>(sB, sH, perm, src_m, dst_m, dis_m, E);

    // h2 = relu(agg1) @ W2 -> sC ; agg2 -> sA  (embed1 = relu(sA))
    k_gemm<<<gGemm, 256, 0, stream>>>(sA, W2, nullptr, sC, N, 128, 1, 0);
    k_agg_init<<<gInit, 256, 0, stream>>>(sA, sC, nullptr, inv_m, b2, N);
    k_agg_scatter<<<gScat, 256, 0, stream>>>(sA, sC, nullptr, src_m, dst_m, dis_m, E);

    // h2b = relu(agg1b) @ W2 -> sC ; agg2b -> sB  (embed1b = relu(sB))
    k_gemm<<<gGemm, 256, 0, stream>>>(sB, W2, nullptr, sC, N, 128, 1, 0);
    k_agg_init<<<gInit, 256, 0, stream>>>(sB, sC, nullptr, inv_m, b2, N);
    k_agg_scatter<<<gScat, 256, 0, stream>>>(sB, sC, nullptr, src_m, dst_m, dis_m, E);

    // h3 = relu(agg2) @ W3 -> sH ; embed2 = hop-agg -> sE
    k_gemm<<<gGemm, 256, 0, stream>>>(sA, W3, nullptr, sH, N, 128, 1, 0);
    k_agg_init<<<gInit, 256, 0, stream>>>(sE, sH, nullptr, inv_h, b3, N);
    k_agg_scatter<<<gScat, 256, 0, stream>>>(sE, sH, nullptr, src_h, dst_h, dis_h, E);

    // t = relu(relu(agg2) @ M1 + mb1) -> sH ; embed3 = t @ M2 + mb2 -> sC
    k_gemm<<<gGemm, 256, 0, stream>>>(sA, M1, mb1, sH, N, 128, 1, 1);
    k_gemm<<<gGemm, 256, 0, stream>>>(sH, M2, mb2, sC, N, 128, 0, 0);

    // classifier: hc = relu(agg2) @ Wc -> sF ; agg -> d_out cols 0..9
    k_gemm10<<<gN, 256, 0, stream>>>(sA, Wc, sF, N, 1);
    k_agg10_init<<<gI10, 256, 0, stream>>>(out, sF, inv_m, bc, N);
    k_agg10_scatter<<<gS10, 256, 0, stream>>>(out, sF, src_m, dst_m, dis_m, E);

    // h3b = relu(agg2b) @ W3 -> sA ; embed2b = hop-agg -> sH
    k_gemm<<<gGemm, 256, 0, stream>>>(sB, W3, nullptr, sA, N, 128, 1, 0);
    k_agg_init<<<gInit, 256, 0, stream>>>(sH, sA, nullptr, inv_h, b3, N);
    k_agg_scatter<<<gScat, 256, 0, stream>>>(sH, sA, nullptr, src_h, dst_h, dis_h, E);

    // v = embed3 @ Wd -> sB ; scores -> d_out cols 10,11
    k_gemm<<<gGemm, 256, 0, stream>>>(sC, Wd, nullptr, sB, N, 128, 0, 0);
    k_score<<<gScore, 256, 0, stream>>>(sB, sE, sH, out, N);
}

// Round 2
// 2597.450 us; speedup vs baseline: 2.0650x; 2.0650x over previous
//
#include <hip/hip_runtime.h>
#include <cstddef>

#define NN 100000
#define NE 1600000
#define KIN 512
#define FD 128
#define NC 10

// ---------------- degree / CSR-build kernels ----------------
__global__ void k_zero2(int* __restrict__ a, int* __restrict__ b, int n) {
    int i = blockIdx.x * 256 + threadIdx.x;
    if (i < n) { a[i] = 0; b[i] = 0; }
}

__global__ void k_hist_int(const int* __restrict__ dst, int* __restrict__ cnt, int E) {
    int e = blockIdx.x * 256 + threadIdx.x;
    if (e < E) atomicAdd(&cnt[dst[e]], 1);
}

__global__ void k_finalize(const int* __restrict__ cnt, float* __restrict__ dis,
                           float* __restrict__ inv, int n) {
    int i = blockIdx.x * 256 + threadIdx.x;
    if (i < n) {
        float d = (float)cnt[i] + 1.0f;   // +1 self loop
        dis[i] = rsqrtf(d);
        inv[i] = 1.0f / d;
    }
}

// single-block exclusive scan of n counts -> offs[0..n], cursor copy
__global__ __launch_bounds__(1024) void k_scan(const int* __restrict__ cnt,
                                               int* __restrict__ offs,
                                               int* __restrict__ cursor, int n) {
    __shared__ int sums[1024];
    int tid = threadIdx.x;
    int chunk = (n + 1023) / 1024;
    int b = tid * chunk;
    int e = min(b + chunk, n);
    int s = 0;
    for (int i = b; i < e; ++i) s += cnt[i];
    sums[tid] = s;
    __syncthreads();
    for (int off = 1; off < 1024; off <<= 1) {
        int v = (tid >= off) ? sums[tid - off] : 0;
        __syncthreads();
        sums[tid] += v;
        __syncthreads();
    }
    int run = (tid == 0) ? 0 : sums[tid - 1];
    for (int i = b; i < e; ++i) {
        offs[i] = run; cursor[i] = run;
        run += cnt[i];
    }
    if (tid == 1023) { offs[n] = run; cursor[n] = run; }
}

__global__ void k_fill(const int* __restrict__ src, const int* __restrict__ dst,
                       const float* __restrict__ dis, int* __restrict__ cursor,
                       int* __restrict__ csr_src, float* __restrict__ csr_w, int E) {
    int e = blockIdx.x * 256 + threadIdx.x;
    if (e >= E) return;
    int s = src[e], d = dst[e];
    int pos = atomicAdd(&cursor[d], 1);
    csr_src[pos] = s;
    csr_w[pos] = dis[s] * dis[d];
}

// ---------------- tiled fp32 GEMM: C[M x 128] = op(A[M x K]) @ B[K x 128] ----------------
__global__ __launch_bounds__(256) void k_gemm(
    const float* __restrict__ A, const float* __restrict__ B,
    const float* __restrict__ bias, float* __restrict__ C,
    int M, int K, int relu_a, int relu_out) {
    __shared__ __align__(16) float As[16][68];   // transposed, padded
    __shared__ __align__(16) float Bs[16][128];

    const int tid = threadIdx.x;
    const int row0 = blockIdx.x * 64;
    const int tx = tid & 31;    // col group: 4 cols each
    const int ty = tid >> 5;    // row group: 8 rows each

    float acc[8][4];
#pragma unroll
    for (int r = 0; r < 8; ++r)
#pragma unroll
        for (int c = 0; c < 4; ++c) acc[r][c] = 0.0f;

    const int lrow = tid >> 2;
    const int lk = (tid & 3) * 4;

    for (int k0 = 0; k0 < K; k0 += 16) {
        float4 av = make_float4(0.f, 0.f, 0.f, 0.f);
        int ar = row0 + lrow;
        if (ar < M) av = *(const float4*)(A + (size_t)ar * K + k0 + lk);
        if (relu_a) {
            av.x = fmaxf(av.x, 0.f); av.y = fmaxf(av.y, 0.f);
            av.z = fmaxf(av.z, 0.f); av.w = fmaxf(av.w, 0.f);
        }
        As[lk + 0][lrow] = av.x;
        As[lk + 1][lrow] = av.y;
        As[lk + 2][lrow] = av.z;
        As[lk + 3][lrow] = av.w;
#pragma unroll
        for (int i = 0; i < 2; ++i) {
            int f4 = tid + i * 256;
            int bk = f4 >> 5;
            int bc = (f4 & 31) * 4;
            *(float4*)&Bs[bk][bc] = *(const float4*)(B + (size_t)(k0 + bk) * 128 + bc);
        }
        __syncthreads();
#pragma unroll
        for (int k = 0; k < 16; ++k) {
            float4 a0 = *(const float4*)&As[k][ty * 8];
            float4 a1 = *(const float4*)&As[k][ty * 8 + 4];
            float4 bv = *(const float4*)&Bs[k][tx * 4];
            float a[8] = {a0.x, a0.y, a0.z, a0.w, a1.x, a1.y, a1.z, a1.w};
            float b[4] = {bv.x, bv.y, bv.z, bv.w};
#pragma unroll
            for (int r = 0; r < 8; ++r)
#pragma unroll
                for (int c = 0; c < 4; ++c)
                    acc[r][c] = fmaf(a[r], b[c], acc[r][c]);
        }
        __syncthreads();
    }

    float4 bv = make_float4(0.f, 0.f, 0.f, 0.f);
    if (bias) bv = *(const float4*)(bias + tx * 4);
#pragma unroll
    for (int r = 0; r < 8; ++r) {
        int rr = row0 + ty * 8 + r;
        if (rr < M) {
            float4 o;
            o.x = acc[r][0] + bv.x; o.y = acc[r][1] + bv.y;
            o.z = acc[r][2] + bv.z; o.w = acc[r][3] + bv.w;
            if (relu_out) {
                o.x = fmaxf(o.x, 0.f); o.y = fmaxf(o.y, 0.f);
                o.z = fmaxf(o.z, 0.f); o.w = fmaxf(o.w, 0.f);
            }
            *(float4*)(C + (size_t)rr * 128 + tx * 4) = o;
        }
    }
}

// ---------------- small GEMM: C[M x 10] = op(A[M x 128]) @ W[128 x 10] ----------------
__global__ __launch_bounds__(256) void k_gemm10(
    const float* __restrict__ A, const float* __restrict__ W,
    float* __restrict__ C, int M, int relu_a) {
    __shared__ float Ws[128 * 10];
    int tid = threadIdx.x;
    for (int i = tid; i < 1280; i += 256) Ws[i] = W[i];
    __syncthreads();
    int row = blockIdx.x * 256 + tid;
    if (row >= M) return;
    float acc[10];
#pragma unroll
    for (int c = 0; c < 10; ++c) acc[c] = 0.0f;
    const float* a = A + (size_t)row * 128;
    for (int k = 0; k < 128; k += 4) {
        float4 av = *(const float4*)(a + k);
        if (relu_a) {
            av.x = fmaxf(av.x, 0.f); av.y = fmaxf(av.y, 0.f);
            av.z = fmaxf(av.z, 0.f); av.w = fmaxf(av.w, 0.f);
        }
        float vs[4] = {av.x, av.y, av.z, av.w};
#pragma unroll
        for (int j = 0; j < 4; ++j)
#pragma unroll
            for (int c = 0; c < 10; ++c)
                acc[c] = fmaf(vs[j], Ws[(k + j) * 10 + c], acc[c]);
    }
    float* o = C + (size_t)row * 10;
#pragma unroll
    for (int c = 0; c < 10; ++c) o[c] = acc[c];
}

// ---------------- GCN aggregation, CSR gather (F=128) ----------------
// one wave per node; lane handles 2 contiguous feats (float2).
// out[n,:] = sum_{e in in(n)} h[permIdx?[src_e]] * w_e  +  h[permIdx?[n]]*inv[n] + bias
__global__ __launch_bounds__(256) void k_agg_gather(
    float* __restrict__ out, const float* __restrict__ h,
    const int* __restrict__ permIdx,
    const int* __restrict__ offs, const int* __restrict__ csr_src,
    const float* __restrict__ csr_w,
    const float* __restrict__ inv, const float* __restrict__ bias, int n) {
    int gid = blockIdx.x * 256 + threadIdx.x;
    int node = gid >> 6;
    int lane = gid & 63;
    if (node >= n) return;
    const float2* h2 = (const float2*)h;
    int beg = offs[node], end = offs[node + 1];

    int sn = permIdx ? permIdx[node] : node;
    float2 hv = h2[(size_t)sn * 64 + lane];
    float2 bv = ((const float2*)bias)[lane];
    float iv = inv[node];
    float ax = fmaf(hv.x, iv, bv.x);
    float ay = fmaf(hv.y, iv, bv.y);

    for (int c = beg; c < end; c += 64) {
        int idx = c + lane;
        int s = 0; float w = 0.0f;
        if (idx < end) {
            s = csr_src[idx];
            w = csr_w[idx];
            if (permIdx) s = permIdx[s];
        }
        int cnt = min(64, end - c);
#pragma unroll 4
        for (int j = 0; j < cnt; ++j) {
            int sj = __shfl(s, j);
            float wj = __shfl(w, j);
            float2 hj = h2[(size_t)sj * 64 + lane];
            ax = fmaf(hj.x, wj, ax);
            ay = fmaf(hj.y, wj, ay);
        }
    }
    float2 o; o.x = ax; o.y = ay;
    ((float2*)out)[(size_t)node * 64 + lane] = o;
}

// ---------------- classifier aggregation gather (F=10, writes d_out stride 12) ----------------
__global__ __launch_bounds__(256) void k_agg10_gather(
    float* __restrict__ out, const float* __restrict__ hc,
    const int* __restrict__ offs, const int* __restrict__ csr_src,
    const float* __restrict__ csr_w,
    const float* __restrict__ inv, const float* __restrict__ bc, int n) {
    int gid = blockIdx.x * 256 + threadIdx.x;
    int node = gid >> 6;
    int lane = gid & 63;
    if (node >= n) return;
    int beg = offs[node], end = offs[node + 1];
    float acc = 0.0f;
    if (lane < 10) acc = fmaf(hc[(size_t)node * 10 + lane], inv[node], bc[lane]);
    for (int c = beg; c < end; c += 64) {
        int idx = c + lane;
        int s = 0; float w = 0.0f;
        if (idx < end) { s = csr_src[idx]; w = csr_w[idx]; }
        int cnt = min(64, end - c);
        for (int j = 0; j < cnt; ++j) {
            int sj = __shfl(s, j);
            float wj = __shfl(w, j);
            if (lane < 10) acc = fmaf(hc[(size_t)sj * 10 + lane], wj, acc);
        }
    }
    if (lane < 10) out[(size_t)node * 12 + lane] = acc;
}

// ---------------- bilinear scores ----------------
__global__ void k_score(const float* __restrict__ v, const float* __restrict__ e2,
                        const float* __restrict__ e2b, float* __restrict__ out, int n) {
    int tid = threadIdx.x;
    int node = blockIdx.x * 4 + (tid >> 6);
    int lane = tid & 63;
    if (node >= n) return;
    const float* vp = v + (size_t)node * 128;
    const float* ap = e2 + (size_t)node * 128;
    const float* bp = e2b + (size_t)node * 128;
    float v0 = vp[lane], v1 = vp[lane + 64];
    float s1 = v0 * ap[lane] + v1 * ap[lane + 64];
    float s2 = v0 * bp[lane] + v1 * bp[lane + 64];
#pragma unroll
    for (int off = 32; off > 0; off >>= 1) {
        s1 += __shfl_xor(s1, off);
        s2 += __shfl_xor(s2, off);
    }
    if (lane == 0) {
        out[(size_t)node * 12 + 10] = 1.0f / (1.0f + __expf(-s1));
        out[(size_t)node * 12 + 11] = 1.0f / (1.0f + __expf(-s2));
    }
}

extern "C" void kernel_launch(void* const* d_in, const int* in_sizes, int n_in,
                              void* d_out, int out_size, void* d_ws, size_t ws_size,
                              hipStream_t stream) {
    const float* x   = (const float*)d_in[0];
    const int*   ei  = (const int*)d_in[1];
    const int*   eih = (const int*)d_in[2];
    const int*   perm = (const int*)d_in[4];
    const float* W1 = (const float*)d_in[5];
    const float* b1 = (const float*)d_in[6];
    const float* W2 = (const float*)d_in[7];
    const float* b2 = (const float*)d_in[8];
    const float* W3 = (const float*)d_in[9];
    const float* b3 = (const float*)d_in[10];
    const float* M1 = (const float*)d_in[11];
    const float* mb1 = (const float*)d_in[12];
    const float* M2 = (const float*)d_in[13];
    const float* mb2 = (const float*)d_in[14];
    const float* Wc = (const float*)d_in[15];
    const float* bc = (const float*)d_in[16];
    const float* Wd = (const float*)d_in[17];
    float* out = (float*)d_out;

    const int N = NN, E = NE;
    const int* src_m = ei;
    const int* dst_m = ei + E;
    const int* src_h = eih;
    const int* dst_h = eih + E;

    // ---- workspace layout ----
    char* w = (char*)d_ws;
    float* dis_m = (float*)w;                w += (size_t)N * 4;
    float* inv_m = (float*)w;                w += (size_t)N * 4;
    float* dis_h = (float*)w;                w += (size_t)N * 4;
    float* inv_h = (float*)w;                w += (size_t)N * 4;
    int* cnt_m   = (int*)w;                  w += (size_t)N * 4;
    int* cnt_h   = (int*)w;                  w += (size_t)N * 4;
    int* offs_m  = (int*)w;                  w += (size_t)(N + 1) * 4;
    int* offs_h  = (int*)w;                  w += (size_t)(N + 1) * 4;
    int* cur_m   = (int*)w;                  w += (size_t)(N + 1) * 4;
    int* cur_h   = (int*)w;                  w += (size_t)(N + 1) * 4;
    int* csr_src_m = (int*)w;                w += (size_t)E * 4;
    float* csr_w_m = (float*)w;              w += (size_t)E * 4;
    int* csr_src_h = (int*)w;                w += (size_t)E * 4;
    float* csr_w_h = (float*)w;              w += (size_t)E * 4;
    const size_t SLOT = (size_t)N * 128;
    float* S0 = (float*)w;                   w += SLOT * 4;
    float* S1 = (float*)w;                   w += SLOT * 4;
    float* S2 = (float*)w;                   w += SLOT * 4;
    float* S3 = (float*)w;                   w += SLOT * 4;
    float* sF = (float*)w;                   w += (size_t)N * 10 * 4;

    const int gN = (N + 255) / 256;
    const int gE = (E + 255) / 256;
    const int gGemm = (N + 63) / 64;
    const int gWave = (N * 64 + 255) / 256;      // wave-per-node kernels
    const int gScore = (N + 3) / 4;

    // ---- build CSR for both graphs ----
    k_zero2<<<gN, 256, 0, stream>>>(cnt_m, cnt_h, N);
    k_hist_int<<<gE, 256, 0, stream>>>(dst_m, cnt_m, E);
    k_hist_int<<<gE, 256, 0, stream>>>(dst_h, cnt_h, E);
    k_finalize<<<gN, 256, 0, stream>>>(cnt_m, dis_m, inv_m, N);
    k_finalize<<<gN, 256, 0, stream>>>(cnt_h, dis_h, inv_h, N);
    k_scan<<<1, 1024, 0, stream>>>(cnt_m, offs_m, cur_m, N);
    k_scan<<<1, 1024, 0, stream>>>(cnt_h, offs_h, cur_h, N);
    k_fill<<<gE, 256, 0, stream>>>(src_m, dst_m, dis_m, cur_m, csr_src_m, csr_w_m, E);
    k_fill<<<gE, 256, 0, stream>>>(src_h, dst_h, dis_h, cur_h, csr_src_h, csr_w_h, E);

    // ---- h1 = x @ W1 -> S0 (shared; bad branch via perm indirection) ----
    k_gemm<<<gGemm, 256, 0, stream>>>(x, W1, nullptr, S0, N, KIN, 0, 0);

    // agg1 -> S1 ; agg1b -> S2
    k_agg_gather<<<gWave, 256, 0, stream>>>(S1, S0, nullptr, offs_m, csr_src_m, csr_w_m, inv_m, b1, N);
    k_agg_gather<<<gWave, 256, 0, stream>>>(S2, S0, perm, offs_m, csr_src_m, csr_w_m, inv_m, b1, N);

    // h2 = relu(S1)@W2 -> S3 ; agg2 -> S1
    k_gemm<<<gGemm, 256, 0, stream>>>(S1, W2, nullptr, S3, N, 128, 1, 0);
    k_agg_gather<<<gWave, 256, 0, stream>>>(S1, S3, nullptr, offs_m, csr_src_m, csr_w_m, inv_m, b2, N);

    // h2b = relu(S2)@W2 -> S3 ; agg2b -> S2
    k_gemm<<<gGemm, 256, 0, stream>>>(S2, W2, nullptr, S3, N, 128, 1, 0);
    k_agg_gather<<<gWave, 256, 0, stream>>>(S2, S3, nullptr, offs_m, csr_src_m, csr_w_m, inv_m, b2, N);

    // h3 = relu(S1)@W3 -> S0 ; embed2 (hop graph) -> S3
    k_gemm<<<gGemm, 256, 0, stream>>>(S1, W3, nullptr, S0, N, 128, 1, 0);
    k_agg_gather<<<gWave, 256, 0, stream>>>(S3, S0, nullptr, offs_h, csr_src_h, csr_w_h, inv_h, b3, N);

    // classifier: hc = relu(S1)@Wc -> sF ; agg -> out cols 0..9
    k_gemm10<<<gN, 256, 0, stream>>>(S1, Wc, sF, N, 1);
    k_agg10_gather<<<gWave, 256, 0, stream>>>(out, sF, offs_m, csr_src_m, csr_w_m, inv_m, bc, N);

    // t = relu(relu(S1)@M1+mb1) -> S0 ; embed3 = S0@M2+mb2 -> S1
    k_gemm<<<gGemm, 256, 0, stream>>>(S1, M1, mb1, S0, N, 128, 1, 1);
    k_gemm<<<gGemm, 256, 0, stream>>>(S0, M2, mb2, S1, N, 128, 0, 0);

    // h3b = relu(S2)@W3 -> S0 ; embed2b -> S2
    k_gemm<<<gGemm, 256, 0, stream>>>(S2, W3, nullptr, S0, N, 128, 1, 0);
    k_agg_gather<<<gWave, 256, 0, stream>>>(S2, S0, nullptr, offs_h, csr_src_h, csr_w_h, inv_h, b3, N);

    // v = embed3(S1)@Wd -> S0 ; scores -> out cols 10,11
    k_gemm<<<gGemm, 256, 0, stream>>>(S1, Wd, nullptr, S0, N, 128, 0, 0);
    k_score<<<gScore, 256, 0, stream>>>(S0, S3, S2, out, N);
}

// Round 3
// 2162.506 us; speedup vs baseline: 2.4803x; 1.2011x over previous
//
#include <hip/hip_runtime.h>
#include <cstddef>

#define NN 100000
#define NE 1600000
#define KIN 512
#define FD 128
#define NC 10
#define SCAN_CHUNK 1024

// ---------------- degree / CSR-build kernels ----------------
__global__ void k_zero2(int* __restrict__ a, int* __restrict__ b, int n) {
    int i = blockIdx.x * 256 + threadIdx.x;
    if (i < n) { a[i] = 0; b[i] = 0; }
}

__global__ void k_hist_int(const int* __restrict__ dst, int* __restrict__ cnt, int E) {
    int e = blockIdx.x * 256 + threadIdx.x;
    if (e < E) atomicAdd(&cnt[dst[e]], 1);
}

__global__ void k_finalize(const int* __restrict__ cnt, float* __restrict__ dis,
                           float* __restrict__ inv, int n) {
    int i = blockIdx.x * 256 + threadIdx.x;
    if (i < n) {
        float d = (float)cnt[i] + 1.0f;   // +1 self loop
        dis[i] = rsqrtf(d);
        inv[i] = 1.0f / d;
    }
}

// ---------------- 3-phase device-wide exclusive scan ----------------
// phase A: per-block chunk sums
__global__ __launch_bounds__(256) void k_scan_partial(const int* __restrict__ cnt,
                                                      int* __restrict__ part, int n) {
    __shared__ int red[256];
    int base = blockIdx.x * SCAN_CHUNK;
    int tid = threadIdx.x;
    int s = 0;
    for (int i = tid; i < SCAN_CHUNK; i += 256) {
        int g = base + i;
        if (g < n) s += cnt[g];
    }
    red[tid] = s;
    __syncthreads();
    for (int off = 128; off > 0; off >>= 1) {
        if (tid < off) red[tid] += red[tid + off];
        __syncthreads();
    }
    if (tid == 0) part[blockIdx.x] = red[0];
}

// phase B: single small block scans partials (B <= 1024), writes offs[n]
__global__ __launch_bounds__(1024) void k_scan_part(int* __restrict__ part,
                                                    int* __restrict__ offs,
                                                    int* __restrict__ cursor,
                                                    int B, int n) {
    __shared__ int s[1024];
    int tid = threadIdx.x;
    int v0 = (tid < B) ? part[tid] : 0;
    s[tid] = v0;
    __syncthreads();
    for (int off = 1; off < 1024; off <<= 1) {
        int v = (tid >= off) ? s[tid - off] : 0;
        __syncthreads();
        s[tid] += v;
        __syncthreads();
    }
    if (tid < B) part[tid] = s[tid] - v0;   // exclusive
    if (tid == B - 1) { offs[n] = s[tid]; cursor[n] = s[tid]; }
}

// phase C: write exclusive offsets + cursor
__global__ __launch_bounds__(256) void k_scan_final(const int* __restrict__ cnt,
                                                    const int* __restrict__ part,
                                                    int* __restrict__ offs,
                                                    int* __restrict__ cursor, int n) {
    __shared__ int tsum[256];
    int base = blockIdx.x * SCAN_CHUNK;
    int tid = threadIdx.x;
    int g0 = base + tid * 4;
    int c[4];
    int s = 0;
#pragma unroll
    for (int j = 0; j < 4; ++j) {
        int g = g0 + j;
        c[j] = (g < n) ? cnt[g] : 0;
        s += c[j];
    }
    tsum[tid] = s;
    __syncthreads();
    for (int off = 1; off < 256; off <<= 1) {
        int v = (tid >= off) ? tsum[tid - off] : 0;
        __syncthreads();
        tsum[tid] += v;
        __syncthreads();
    }
    int run = part[blockIdx.x] + tsum[tid] - s;
#pragma unroll
    for (int j = 0; j < 4; ++j) {
        int g = g0 + j;
        if (g < n) { offs[g] = run; cursor[g] = run; run += c[j]; }
    }
}

__global__ void k_fill(const int* __restrict__ src, const int* __restrict__ dst,
                       const float* __restrict__ dis, int* __restrict__ cursor,
                       int* __restrict__ csr_src, float* __restrict__ csr_w, int E) {
    int e = blockIdx.x * 256 + threadIdx.x;
    if (e >= E) return;
    int s = src[e], d = dst[e];
    int pos = atomicAdd(&cursor[d], 1);
    csr_src[pos] = s;
    csr_w[pos] = dis[s] * dis[d];
}

// ---------------- tiled fp32 GEMM: C[M x 128] = op(A[M x K]) @ B[K x 128] ----------------
__global__ __launch_bounds__(256) void k_gemm(
    const float* __restrict__ A, const float* __restrict__ B,
    const float* __restrict__ bias, float* __restrict__ C,
    int M, int K, int relu_a, int relu_out) {
    __shared__ __align__(16) float As[16][68];   // transposed, padded
    __shared__ __align__(16) float Bs[16][128];

    const int tid = threadIdx.x;
    const int row0 = blockIdx.x * 64;
    const int tx = tid & 31;
    const int ty = tid >> 5;

    float acc[8][4];
#pragma unroll
    for (int r = 0; r < 8; ++r)
#pragma unroll
        for (int c = 0; c < 4; ++c) acc[r][c] = 0.0f;

    const int lrow = tid >> 2;
    const int lk = (tid & 3) * 4;

    for (int k0 = 0; k0 < K; k0 += 16) {
        float4 av = make_float4(0.f, 0.f, 0.f, 0.f);
        int ar = row0 + lrow;
        if (ar < M) av = *(const float4*)(A + (size_t)ar * K + k0 + lk);
        if (relu_a) {
            av.x = fmaxf(av.x, 0.f); av.y = fmaxf(av.y, 0.f);
            av.z = fmaxf(av.z, 0.f); av.w = fmaxf(av.w, 0.f);
        }
        As[lk + 0][lrow] = av.x;
        As[lk + 1][lrow] = av.y;
        As[lk + 2][lrow] = av.z;
        As[lk + 3][lrow] = av.w;
#pragma unroll
        for (int i = 0; i < 2; ++i) {
            int f4 = tid + i * 256;
            int bk = f4 >> 5;
            int bc = (f4 & 31) * 4;
            *(float4*)&Bs[bk][bc] = *(const float4*)(B + (size_t)(k0 + bk) * 128 + bc);
        }
        __syncthreads();
#pragma unroll
        for (int k = 0; k < 16; ++k) {
            float4 a0 = *(const float4*)&As[k][ty * 8];
            float4 a1 = *(const float4*)&As[k][ty * 8 + 4];
            float4 bv = *(const float4*)&Bs[k][tx * 4];
            float a[8] = {a0.x, a0.y, a0.z, a0.w, a1.x, a1.y, a1.z, a1.w};
            float b[4] = {bv.x, bv.y, bv.z, bv.w};
#pragma unroll
            for (int r = 0; r < 8; ++r)
#pragma unroll
                for (int c = 0; c < 4; ++c)
                    acc[r][c] = fmaf(a[r], b[c], acc[r][c]);
        }
        __syncthreads();
    }

    float4 bv = make_float4(0.f, 0.f, 0.f, 0.f);
    if (bias) bv = *(const float4*)(bias + tx * 4);
#pragma unroll
    for (int r = 0; r < 8; ++r) {
        int rr = row0 + ty * 8 + r;
        if (rr < M) {
            float4 o;
            o.x = acc[r][0] + bv.x; o.y = acc[r][1] + bv.y;
            o.z = acc[r][2] + bv.z; o.w = acc[r][3] + bv.w;
            if (relu_out) {
                o.x = fmaxf(o.x, 0.f); o.y = fmaxf(o.y, 0.f);
                o.z = fmaxf(o.z, 0.f); o.w = fmaxf(o.w, 0.f);
            }
            *(float4*)(C + (size_t)rr * 128 + tx * 4) = o;
        }
    }
}

// ---------------- small GEMM: C[M x 10] = op(A[M x 128]) @ W[128 x 10] ----------------
__global__ __launch_bounds__(256) void k_gemm10(
    const float* __restrict__ A, const float* __restrict__ W,
    float* __restrict__ C, int M, int relu_a) {
    __shared__ float Ws[128 * 10];
    int tid = threadIdx.x;
    for (int i = tid; i < 1280; i += 256) Ws[i] = W[i];
    __syncthreads();
    int row = blockIdx.x * 256 + tid;
    if (row >= M) return;
    float acc[10];
#pragma unroll
    for (int c = 0; c < 10; ++c) acc[c] = 0.0f;
    const float* a = A + (size_t)row * 128;
    for (int k = 0; k < 128; k += 4) {
        float4 av = *(const float4*)(a + k);
        if (relu_a) {
            av.x = fmaxf(av.x, 0.f); av.y = fmaxf(av.y, 0.f);
            av.z = fmaxf(av.z, 0.f); av.w = fmaxf(av.w, 0.f);
        }
        float vs[4] = {av.x, av.y, av.z, av.w};
#pragma unroll
        for (int j = 0; j < 4; ++j)
#pragma unroll
            for (int c = 0; c < 10; ++c)
                acc[c] = fmaf(vs[j], Ws[(k + j) * 10 + c], acc[c]);
    }
    float* o = C + (size_t)row * 10;
#pragma unroll
    for (int c = 0; c < 10; ++c) o[c] = acc[c];
}

// ---------------- GCN aggregation, CSR gather (F=128) ----------------
__global__ __launch_bounds__(256) void k_agg_gather(
    float* __restrict__ out, const float* __restrict__ h,
    const int* __restrict__ permIdx,
    const int* __restrict__ offs, const int* __restrict__ csr_src,
    const float* __restrict__ csr_w,
    const float* __restrict__ inv, const float* __restrict__ bias, int n) {
    int gid = blockIdx.x * 256 + threadIdx.x;
    int node = gid >> 6;
    int lane = gid & 63;
    if (node >= n) return;
    const float2* h2 = (const float2*)h;
    int beg = offs[node], end = offs[node + 1];

    int sn = permIdx ? permIdx[node] : node;
    float2 hv = h2[(size_t)sn * 64 + lane];
    float2 bv = ((const float2*)bias)[lane];
    float iv = inv[node];
    float ax = fmaf(hv.x, iv, bv.x);
    float ay = fmaf(hv.y, iv, bv.y);

    for (int c = beg; c < end; c += 64) {
        int idx = c + lane;
        int s = 0; float w = 0.0f;
        if (idx < end) {
            s = csr_src[idx];
            w = csr_w[idx];
            if (permIdx) s = permIdx[s];
        }
        int cnt = min(64, end - c);
#pragma unroll 4
        for (int j = 0; j < cnt; ++j) {
            int sj = __shfl(s, j);
            float wj = __shfl(w, j);
            float2 hj = h2[(size_t)sj * 64 + lane];
            ax = fmaf(hj.x, wj, ax);
            ay = fmaf(hj.y, wj, ay);
        }
    }
    float2 o; o.x = ax; o.y = ay;
    ((float2*)out)[(size_t)node * 64 + lane] = o;
}

// ---------------- classifier aggregation gather (F=10, writes d_out stride 12) ----------------
__global__ __launch_bounds__(256) void k_agg10_gather(
    float* __restrict__ out, const float* __restrict__ hc,
    const int* __restrict__ offs, const int* __restrict__ csr_src,
    const float* __restrict__ csr_w,
    const float* __restrict__ inv, const float* __restrict__ bc, int n) {
    int gid = blockIdx.x * 256 + threadIdx.x;
    int node = gid >> 6;
    int lane = gid & 63;
    if (node >= n) return;
    int beg = offs[node], end = offs[node + 1];
    float acc = 0.0f;
    if (lane < 10) acc = fmaf(hc[(size_t)node * 10 + lane], inv[node], bc[lane]);
    for (int c = beg; c < end; c += 64) {
        int idx = c + lane;
        int s = 0; float w = 0.0f;
        if (idx < end) { s = csr_src[idx]; w = csr_w[idx]; }
        int cnt = min(64, end - c);
        for (int j = 0; j < cnt; ++j) {
            int sj = __shfl(s, j);
            float wj = __shfl(w, j);
            if (lane < 10) acc = fmaf(hc[(size_t)sj * 10 + lane], wj, acc);
        }
    }
    if (lane < 10) out[(size_t)node * 12 + lane] = acc;
}

// ---------------- bilinear scores ----------------
__global__ void k_score(const float* __restrict__ v, const float* __restrict__ e2,
                        const float* __restrict__ e2b, float* __restrict__ out, int n) {
    int tid = threadIdx.x;
    int node = blockIdx.x * 4 + (tid >> 6);
    int lane = tid & 63;
    if (node >= n) return;
    const float* vp = v + (size_t)node * 128;
    const float* ap = e2 + (size_t)node * 128;
    const float* bp = e2b + (size_t)node * 128;
    float v0 = vp[lane], v1 = vp[lane + 64];
    float s1 = v0 * ap[lane] + v1 * ap[lane + 64];
    float s2 = v0 * bp[lane] + v1 * bp[lane + 64];
#pragma unroll
    for (int off = 32; off > 0; off >>= 1) {
        s1 += __shfl_xor(s1, off);
        s2 += __shfl_xor(s2, off);
    }
    if (lane == 0) {
        out[(size_t)node * 12 + 10] = 1.0f / (1.0f + __expf(-s1));
        out[(size_t)node * 12 + 11] = 1.0f / (1.0f + __expf(-s2));
    }
}

extern "C" void kernel_launch(void* const* d_in, const int* in_sizes, int n_in,
                              void* d_out, int out_size, void* d_ws, size_t ws_size,
                              hipStream_t stream) {
    const float* x   = (const float*)d_in[0];
    const int*   ei  = (const int*)d_in[1];
    const int*   eih = (const int*)d_in[2];
    const int*   perm = (const int*)d_in[4];
    const float* W1 = (const float*)d_in[5];
    const float* b1 = (const float*)d_in[6];
    const float* W2 = (const float*)d_in[7];
    const float* b2 = (const float*)d_in[8];
    const float* W3 = (const float*)d_in[9];
    const float* b3 = (const float*)d_in[10];
    const float* M1 = (const float*)d_in[11];
    const float* mb1 = (const float*)d_in[12];
    const float* M2 = (const float*)d_in[13];
    const float* mb2 = (const float*)d_in[14];
    const float* Wc = (const float*)d_in[15];
    const float* bc = (const float*)d_in[16];
    const float* Wd = (const float*)d_in[17];
    float* out = (float*)d_out;

    const int N = NN, E = NE;
    const int* src_m = ei;
    const int* dst_m = ei + E;
    const int* src_h = eih;
    const int* dst_h = eih + E;

    // ---- workspace layout ----
    char* w = (char*)d_ws;
    float* dis_m = (float*)w;                w += (size_t)N * 4;
    float* inv_m = (float*)w;                w += (size_t)N * 4;
    float* dis_h = (float*)w;                w += (size_t)N * 4;
    float* inv_h = (float*)w;                w += (size_t)N * 4;
    int* cnt_m   = (int*)w;                  w += (size_t)N * 4;
    int* cnt_h   = (int*)w;                  w += (size_t)N * 4;
    int* offs_m  = (int*)w;                  w += (size_t)(N + 1) * 4;
    int* offs_h  = (int*)w;                  w += (size_t)(N + 1) * 4;
    int* cur_m   = (int*)w;                  w += (size_t)(N + 1) * 4;
    int* cur_h   = (int*)w;                  w += (size_t)(N + 1) * 4;
    int* part_m  = (int*)w;                  w += 1024 * 4;
    int* part_h  = (int*)w;                  w += 1024 * 4;
    int* csr_src_m = (int*)w;                w += (size_t)E * 4;
    float* csr_w_m = (float*)w;              w += (size_t)E * 4;
    int* csr_src_h = (int*)w;                w += (size_t)E * 4;
    float* csr_w_h = (float*)w;              w += (size_t)E * 4;
    const size_t SLOT = (size_t)N * 128;
    float* S0 = (float*)w;                   w += SLOT * 4;
    float* S1 = (float*)w;                   w += SLOT * 4;
    float* S2 = (float*)w;                   w += SLOT * 4;
    float* S3 = (float*)w;                   w += SLOT * 4;
    float* sF = (float*)w;                   w += (size_t)N * 10 * 4;

    const int gN = (N + 255) / 256;
    const int gE = (E + 255) / 256;
    const int gGemm = (N + 63) / 64;
    const int gWave = (N * 64 + 255) / 256;
    const int gScore = (N + 3) / 4;
    const int gScan = (N + SCAN_CHUNK - 1) / SCAN_CHUNK;   // 98

    // ---- build CSR for both graphs ----
    k_zero2<<<gN, 256, 0, stream>>>(cnt_m, cnt_h, N);
    k_hist_int<<<gE, 256, 0, stream>>>(dst_m, cnt_m, E);
    k_hist_int<<<gE, 256, 0, stream>>>(dst_h, cnt_h, E);
    k_finalize<<<gN, 256, 0, stream>>>(cnt_m, dis_m, inv_m, N);
    k_finalize<<<gN, 256, 0, stream>>>(cnt_h, dis_h, inv_h, N);
    k_scan_partial<<<gScan, 256, 0, stream>>>(cnt_m, part_m, N);
    k_scan_partial<<<gScan, 256, 0, stream>>>(cnt_h, part_h, N);
    k_scan_part<<<1, 1024, 0, stream>>>(part_m, offs_m, cur_m, gScan, N);
    k_scan_part<<<1, 1024, 0, stream>>>(part_h, offs_h, cur_h, gScan, N);
    k_scan_final<<<gScan, 256, 0, stream>>>(cnt_m, part_m, offs_m, cur_m, N);
    k_scan_final<<<gScan, 256, 0, stream>>>(cnt_h, part_h, offs_h, cur_h, N);
    k_fill<<<gE, 256, 0, stream>>>(src_m, dst_m, dis_m, cur_m, csr_src_m, csr_w_m, E);
    k_fill<<<gE, 256, 0, stream>>>(src_h, dst_h, dis_h, cur_h, csr_src_h, csr_w_h, E);

    // ---- h1 = x @ W1 -> S0 (shared; bad branch via perm indirection) ----
    k_gemm<<<gGemm, 256, 0, stream>>>(x, W1, nullptr, S0, N, KIN, 0, 0);

    // agg1 -> S1 ; agg1b -> S2
    k_agg_gather<<<gWave, 256, 0, stream>>>(S1, S0, nullptr, offs_m, csr_src_m, csr_w_m, inv_m, b1, N);
    k_agg_gather<<<gWave, 256, 0, stream>>>(S2, S0, perm, offs_m, csr_src_m, csr_w_m, inv_m, b1, N);

    // h2 = relu(S1)@W2 -> S3 ; agg2 -> S1
    k_gemm<<<gGemm, 256, 0, stream>>>(S1, W2, nullptr, S3, N, 128, 1, 0);
    k_agg_gather<<<gWave, 256, 0, stream>>>(S1, S3, nullptr, offs_m, csr_src_m, csr_w_m, inv_m, b2, N);

    // h2b = relu(S2)@W2 -> S3 ; agg2b -> S2
    k_gemm<<<gGemm, 256, 0, stream>>>(S2, W2, nullptr, S3, N, 128, 1, 0);
    k_agg_gather<<<gWave, 256, 0, stream>>>(S2, S3, nullptr, offs_m, csr_src_m, csr_w_m, inv_m, b2, N);

    // h3 = relu(S1)@W3 -> S0 ; embed2 (hop graph) -> S3
    k_gemm<<<gGemm, 256, 0, stream>>>(S1, W3, nullptr, S0, N, 128, 1, 0);
    k_agg_gather<<<gWave, 256, 0, stream>>>(S3, S0, nullptr, offs_h, csr_src_h, csr_w_h, inv_h, b3, N);

    // classifier: hc = relu(S1)@Wc -> sF ; agg -> out cols 0..9
    k_gemm10<<<gN, 256, 0, stream>>>(S1, Wc, sF, N, 1);
    k_agg10_gather<<<gWave, 256, 0, stream>>>(out, sF, offs_m, csr_src_m, csr_w_m, inv_m, bc, N);

    // t = relu(relu(S1)@M1+mb1) -> S0 ; embed3 = S0@M2+mb2 -> S1
    k_gemm<<<gGemm, 256, 0, stream>>>(S1, M1, mb1, S0, N, 128, 1, 1);
    k_gemm<<<gGemm, 256, 0, stream>>>(S0, M2, mb2, S1, N, 128, 0, 0);

    // h3b = relu(S2)@W3 -> S0 ; embed2b -> S2
    k_gemm<<<gGemm, 256, 0, stream>>>(S2, W3, nullptr, S0, N, 128, 1, 0);
    k_agg_gather<<<gWave, 256, 0, stream>>>(S2, S0, nullptr, offs_h, csr_src_h, csr_w_h, inv_h, b3, N);

    // v = embed3(S1)@Wd -> S0 ; scores -> out cols 10,11
    k_gemm<<<gGemm, 256, 0, stream>>>(S1, Wd, nullptr, S0, N, 128, 0, 0);
    k_score<<<gScore, 256, 0, stream>>>(S0, S3, S2, out, N);
}

// Round 4
// 2103.390 us; speedup vs baseline: 2.5500x; 1.0281x over previous
//
#include <hip/hip_runtime.h>
#include <cstddef>

#define NN 100000
#define NE 1600000
#define KIN 512
#define SCAN_CHUNK 1024

typedef __attribute__((ext_vector_type(8))) short bf16x8;   // 8 bf16 = 4 VGPR
typedef __attribute__((ext_vector_type(4))) float f32x4;

__device__ inline unsigned short f2bf_rne(float x) {
    unsigned int u = __float_as_uint(x);
    return (unsigned short)((u + 0x7fffu + ((u >> 16) & 1u)) >> 16);
}
__device__ inline float bf2f(unsigned short h) {
    return __uint_as_float(((unsigned int)h) << 16);
}

// ---------------- degree / CSR-build kernels ----------------
__global__ void k_zero2(int* __restrict__ a, int* __restrict__ b, int n) {
    int i = blockIdx.x * 256 + threadIdx.x;
    if (i < n) { a[i] = 0; b[i] = 0; }
}

__global__ void k_hist_int(const int* __restrict__ dst, int* __restrict__ cnt, int E) {
    int e = blockIdx.x * 256 + threadIdx.x;
    if (e < E) atomicAdd(&cnt[dst[e]], 1);
}

__global__ void k_finalize(const int* __restrict__ cnt, float* __restrict__ dis,
                           float* __restrict__ inv, int n) {
    int i = blockIdx.x * 256 + threadIdx.x;
    if (i < n) {
        float d = (float)cnt[i] + 1.0f;   // +1 self loop
        dis[i] = rsqrtf(d);
        inv[i] = 1.0f / d;
    }
}

// ---------------- 3-phase device-wide exclusive scan ----------------
__global__ __launch_bounds__(256) void k_scan_partial(const int* __restrict__ cnt,
                                                      int* __restrict__ part, int n) {
    __shared__ int red[256];
    int base = blockIdx.x * SCAN_CHUNK;
    int tid = threadIdx.x;
    int s = 0;
    for (int i = tid; i < SCAN_CHUNK; i += 256) {
        int g = base + i;
        if (g < n) s += cnt[g];
    }
    red[tid] = s;
    __syncthreads();
    for (int off = 128; off > 0; off >>= 1) {
        if (tid < off) red[tid] += red[tid + off];
        __syncthreads();
    }
    if (tid == 0) part[blockIdx.x] = red[0];
}

__global__ __launch_bounds__(1024) void k_scan_part(int* __restrict__ part,
                                                    int* __restrict__ offs,
                                                    int* __restrict__ cursor,
                                                    int B, int n) {
    __shared__ int s[1024];
    int tid = threadIdx.x;
    int v0 = (tid < B) ? part[tid] : 0;
    s[tid] = v0;
    __syncthreads();
    for (int off = 1; off < 1024; off <<= 1) {
        int v = (tid >= off) ? s[tid - off] : 0;
        __syncthreads();
        s[tid] += v;
        __syncthreads();
    }
    if (tid < B) part[tid] = s[tid] - v0;   // exclusive
    if (tid == B - 1) { offs[n] = s[tid]; cursor[n] = s[tid]; }
}

__global__ __launch_bounds__(256) void k_scan_final(const int* __restrict__ cnt,
                                                    const int* __restrict__ part,
                                                    int* __restrict__ offs,
                                                    int* __restrict__ cursor, int n) {
    __shared__ int tsum[256];
    int base = blockIdx.x * SCAN_CHUNK;
    int tid = threadIdx.x;
    int g0 = base + tid * 4;
    int c[4];
    int s = 0;
#pragma unroll
    for (int j = 0; j < 4; ++j) {
        int g = g0 + j;
        c[j] = (g < n) ? cnt[g] : 0;
        s += c[j];
    }
    tsum[tid] = s;
    __syncthreads();
    for (int off = 1; off < 256; off <<= 1) {
        int v = (tid >= off) ? tsum[tid - off] : 0;
        __syncthreads();
        tsum[tid] += v;
        __syncthreads();
    }
    int run = part[blockIdx.x] + tsum[tid] - s;
#pragma unroll
    for (int j = 0; j < 4; ++j) {
        int g = g0 + j;
        if (g < n) { offs[g] = run; cursor[g] = run; run += c[j]; }
    }
}

__global__ void k_fill(const int* __restrict__ src, const int* __restrict__ dst,
                       const float* __restrict__ dis, int* __restrict__ cursor,
                       int* __restrict__ csr_src, float* __restrict__ csr_w, int E) {
    int e = blockIdx.x * 256 + threadIdx.x;
    if (e >= E) return;
    int s = src[e], d = dst[e];
    int pos = atomicAdd(&cursor[d], 1);
    csr_src[pos] = s;
    csr_w[pos] = dis[s] * dis[d];
}

// ---------------- weight prep: fp32 [K x 128] -> split-bf16 B-fragment layout ----------------
// frag element j of lane (nn + 16*c) of (ktile, ct) = W[ktile*32 + 8*c + j][ct*16 + nn]
__global__ void k_wprep(const float* __restrict__ W, short* __restrict__ hi,
                        short* __restrict__ lo, int K) {
    int idx = blockIdx.x * 256 + threadIdx.x;
    if (idx >= K * 128) return;
    int k = idx >> 7, n = idx & 127;
    float wv = W[idx];
    unsigned short h = f2bf_rne(wv);
    unsigned short l = f2bf_rne(wv - bf2f(h));
    int ktile = k >> 5, kk = k & 31;
    int c = kk >> 3, j = kk & 7;
    int ct = n >> 4, nn = n & 15;
    int lane = nn + 16 * c;
    size_t dst = (((size_t)ktile * 8 + ct) * 64 + lane) * 8 + j;
    hi[dst] = (short)h;
    lo[dst] = (short)l;
}

// ---------------- MFMA split-bf16 GEMM: C[M x 128] = op(A[M x K]) @ B[K x 128] ----------------
// LDS-free: A-frags loaded direct from global (coalesced 64B/row-pair), converted in-register
// via truncate-split (err ~2^-16); B-frags preconverted in global (L2-broadcast).
__global__ __launch_bounds__(256) void k_gemm_mfma(
    const float* __restrict__ A, const short* __restrict__ Bh,
    const short* __restrict__ Bl, const float* __restrict__ bias,
    float* __restrict__ C, int M, int K, int relu_a, int relu_out) {
    const int wave = threadIdx.x >> 6;
    const int lane = threadIdx.x & 63;
    const int mrow = lane & 15;
    const int kc = lane >> 4;           // 0..3 (k-chunk of 8)
    const int r0 = blockIdx.x * 128 + wave * 32;

    f32x4 acc[2][8];
#pragma unroll
    for (int t = 0; t < 2; ++t)
#pragma unroll
        for (int c = 0; c < 8; ++c) acc[t][c] = (f32x4){0.f, 0.f, 0.f, 0.f};

    const int ra0 = min(r0 + mrow, M - 1);
    const int ra1 = min(r0 + 16 + mrow, M - 1);
    const float* pa0 = A + (size_t)ra0 * K + 8 * kc;
    const float* pa1 = A + (size_t)ra1 * K + 8 * kc;

    const int nkt = K >> 5;
    for (int kt = 0; kt < nkt; ++kt) {
        float4 x00 = *(const float4*)(pa0 + kt * 32);
        float4 x01 = *(const float4*)(pa0 + kt * 32 + 4);
        float4 x10 = *(const float4*)(pa1 + kt * 32);
        float4 x11 = *(const float4*)(pa1 + kt * 32 + 4);
        float v0[8] = {x00.x, x00.y, x00.z, x00.w, x01.x, x01.y, x01.z, x01.w};
        float v1[8] = {x10.x, x10.y, x10.z, x10.w, x11.x, x11.y, x11.z, x11.w};
        if (relu_a) {
#pragma unroll
            for (int j = 0; j < 8; ++j) {
                v0[j] = fmaxf(v0[j], 0.f);
                v1[j] = fmaxf(v1[j], 0.f);
            }
        }
        bf16x8 ah0, al0, ah1, al1;
#pragma unroll
        for (int j = 0; j < 8; ++j) {
            unsigned int u0 = __float_as_uint(v0[j]);
            ah0[j] = (short)(u0 >> 16);
            float r0f = v0[j] - __uint_as_float(u0 & 0xffff0000u);
            al0[j] = (short)(__float_as_uint(r0f) >> 16);
            unsigned int u1 = __float_as_uint(v1[j]);
            ah1[j] = (short)(u1 >> 16);
            float r1f = v1[j] - __uint_as_float(u1 & 0xffff0000u);
            al1[j] = (short)(__float_as_uint(r1f) >> 16);
        }
        const short* bp = Bh + ((size_t)kt * 512 + lane) * 8;
        const short* lp = Bl + ((size_t)kt * 512 + lane) * 8;
#pragma unroll
        for (int ct = 0; ct < 8; ++ct) {
            bf16x8 bh = *(const bf16x8*)(bp + (size_t)ct * 512);
            bf16x8 bl = *(const bf16x8*)(lp + (size_t)ct * 512);
            acc[0][ct] = __builtin_amdgcn_mfma_f32_16x16x32_bf16(ah0, bh, acc[0][ct], 0, 0, 0);
            acc[0][ct] = __builtin_amdgcn_mfma_f32_16x16x32_bf16(al0, bh, acc[0][ct], 0, 0, 0);
            acc[0][ct] = __builtin_amdgcn_mfma_f32_16x16x32_bf16(ah0, bl, acc[0][ct], 0, 0, 0);
            acc[1][ct] = __builtin_amdgcn_mfma_f32_16x16x32_bf16(ah1, bh, acc[1][ct], 0, 0, 0);
            acc[1][ct] = __builtin_amdgcn_mfma_f32_16x16x32_bf16(al1, bh, acc[1][ct], 0, 0, 0);
            acc[1][ct] = __builtin_amdgcn_mfma_f32_16x16x32_bf16(ah1, bl, acc[1][ct], 0, 0, 0);
        }
    }

    float bv[8];
#pragma unroll
    for (int ct = 0; ct < 8; ++ct) bv[ct] = bias ? bias[ct * 16 + mrow] : 0.0f;
#pragma unroll
    for (int t = 0; t < 2; ++t) {
#pragma unroll
        for (int ct = 0; ct < 8; ++ct) {
#pragma unroll
            for (int r = 0; r < 4; ++r) {
                int row = r0 + 16 * t + kc * 4 + r;   // C/D: row=(lane>>4)*4+reg, col=lane&15
                if (row < M) {
                    float v = acc[t][ct][r] + bv[ct];
                    if (relu_out) v = fmaxf(v, 0.f);
                    C[(size_t)row * 128 + ct * 16 + mrow] = v;
                }
            }
        }
    }
}

// ---------------- small GEMM: C[M x 10] = op(A[M x 128]) @ W[128 x 10] ----------------
__global__ __launch_bounds__(256) void k_gemm10(
    const float* __restrict__ A, const float* __restrict__ W,
    float* __restrict__ C, int M, int relu_a) {
    __shared__ float Ws[128 * 10];
    int tid = threadIdx.x;
    for (int i = tid; i < 1280; i += 256) Ws[i] = W[i];
    __syncthreads();
    int row = blockIdx.x * 256 + tid;
    if (row >= M) return;
    float acc[10];
#pragma unroll
    for (int c = 0; c < 10; ++c) acc[c] = 0.0f;
    const float* a = A + (size_t)row * 128;
    for (int k = 0; k < 128; k += 4) {
        float4 av = *(const float4*)(a + k);
        if (relu_a) {
            av.x = fmaxf(av.x, 0.f); av.y = fmaxf(av.y, 0.f);
            av.z = fmaxf(av.z, 0.f); av.w = fmaxf(av.w, 0.f);
        }
        float vs[4] = {av.x, av.y, av.z, av.w};
#pragma unroll
        for (int j = 0; j < 4; ++j)
#pragma unroll
            for (int c = 0; c < 10; ++c)
                acc[c] = fmaf(vs[j], Ws[(k + j) * 10 + c], acc[c]);
    }
    float* o = C + (size_t)row * 10;
#pragma unroll
    for (int c = 0; c < 10; ++c) o[c] = acc[c];
}

// ---------------- GCN aggregation, CSR gather (F=128) ----------------
__global__ __launch_bounds__(256) void k_agg_gather(
    float* __restrict__ out, const float* __restrict__ h,
    const int* __restrict__ permIdx,
    const int* __restrict__ offs, const int* __restrict__ csr_src,
    const float* __restrict__ csr_w,
    const float* __restrict__ inv, const float* __restrict__ bias, int n) {
    int gid = blockIdx.x * 256 + threadIdx.x;
    int node = gid >> 6;
    int lane = gid & 63;
    if (node >= n) return;
    const float2* h2 = (const float2*)h;
    int beg = offs[node], end = offs[node + 1];

    int sn = permIdx ? permIdx[node] : node;
    float2 hv = h2[(size_t)sn * 64 + lane];
    float2 bv = ((const float2*)bias)[lane];
    float iv = inv[node];
    float ax = fmaf(hv.x, iv, bv.x);
    float ay = fmaf(hv.y, iv, bv.y);

    for (int c = beg; c < end; c += 64) {
        int idx = c + lane;
        int s = 0; float w = 0.0f;
        if (idx < end) {
            s = csr_src[idx];
            w = csr_w[idx];
            if (permIdx) s = permIdx[s];
        }
        int cnt = min(64, end - c);
#pragma unroll 4
        for (int j = 0; j < cnt; ++j) {
            int sj = __shfl(s, j);
            float wj = __shfl(w, j);
            float2 hj = h2[(size_t)sj * 64 + lane];
            ax = fmaf(hj.x, wj, ax);
            ay = fmaf(hj.y, wj, ay);
        }
    }
    float2 o; o.x = ax; o.y = ay;
    ((float2*)out)[(size_t)node * 64 + lane] = o;
}

// ---------------- classifier aggregation gather (F=10, writes d_out stride 12) ----------------
__global__ __launch_bounds__(256) void k_agg10_gather(
    float* __restrict__ out, const float* __restrict__ hc,
    const int* __restrict__ offs, const int* __restrict__ csr_src,
    const float* __restrict__ csr_w,
    const float* __restrict__ inv, const float* __restrict__ bc, int n) {
    int gid = blockIdx.x * 256 + threadIdx.x;
    int node = gid >> 6;
    int lane = gid & 63;
    if (node >= n) return;
    int beg = offs[node], end = offs[node + 1];
    float acc = 0.0f;
    if (lane < 10) acc = fmaf(hc[(size_t)node * 10 + lane], inv[node], bc[lane]);
    for (int c = beg; c < end; c += 64) {
        int idx = c + lane;
        int s = 0; float w = 0.0f;
        if (idx < end) { s = csr_src[idx]; w = csr_w[idx]; }
        int cnt = min(64, end - c);
        for (int j = 0; j < cnt; ++j) {
            int sj = __shfl(s, j);
            float wj = __shfl(w, j);
            if (lane < 10) acc = fmaf(hc[(size_t)sj * 10 + lane], wj, acc);
        }
    }
    if (lane < 10) out[(size_t)node * 12 + lane] = acc;
}

// ---------------- bilinear scores ----------------
__global__ void k_score(const float* __restrict__ v, const float* __restrict__ e2,
                        const float* __restrict__ e2b, float* __restrict__ out, int n) {
    int tid = threadIdx.x;
    int node = blockIdx.x * 4 + (tid >> 6);
    int lane = tid & 63;
    if (node >= n) return;
    const float* vp = v + (size_t)node * 128;
    const float* ap = e2 + (size_t)node * 128;
    const float* bp = e2b + (size_t)node * 128;
    float v0 = vp[lane], v1 = vp[lane + 64];
    float s1 = v0 * ap[lane] + v1 * ap[lane + 64];
    float s2 = v0 * bp[lane] + v1 * bp[lane + 64];
#pragma unroll
    for (int off = 32; off > 0; off >>= 1) {
        s1 += __shfl_xor(s1, off);
        s2 += __shfl_xor(s2, off);
    }
    if (lane == 0) {
        out[(size_t)node * 12 + 10] = 1.0f / (1.0f + __expf(-s1));
        out[(size_t)node * 12 + 11] = 1.0f / (1.0f + __expf(-s2));
    }
}

extern "C" void kernel_launch(void* const* d_in, const int* in_sizes, int n_in,
                              void* d_out, int out_size, void* d_ws, size_t ws_size,
                              hipStream_t stream) {
    const float* x   = (const float*)d_in[0];
    const int*   ei  = (const int*)d_in[1];
    const int*   eih = (const int*)d_in[2];
    const int*   perm = (const int*)d_in[4];
    const float* W1 = (const float*)d_in[5];
    const float* b1 = (const float*)d_in[6];
    const float* W2 = (const float*)d_in[7];
    const float* b2 = (const float*)d_in[8];
    const float* W3 = (const float*)d_in[9];
    const float* b3 = (const float*)d_in[10];
    const float* M1 = (const float*)d_in[11];
    const float* mb1 = (const float*)d_in[12];
    const float* M2 = (const float*)d_in[13];
    const float* mb2 = (const float*)d_in[14];
    const float* Wc = (const float*)d_in[15];
    const float* bc = (const float*)d_in[16];
    const float* Wd = (const float*)d_in[17];
    float* out = (float*)d_out;

    const int N = NN, E = NE;
    const int* src_m = ei;
    const int* dst_m = ei + E;
    const int* src_h = eih;
    const int* dst_h = eih + E;

    // ---- workspace layout ----
    char* w = (char*)d_ws;
    float* dis_m = (float*)w;                w += (size_t)N * 4;
    float* inv_m = (float*)w;                w += (size_t)N * 4;
    float* dis_h = (float*)w;                w += (size_t)N * 4;
    float* inv_h = (float*)w;                w += (size_t)N * 4;
    int* cnt_m   = (int*)w;                  w += (size_t)N * 4;
    int* cnt_h   = (int*)w;                  w += (size_t)N * 4;
    int* offs_m  = (int*)w;                  w += (size_t)(N + 1) * 4;
    int* offs_h  = (int*)w;                  w += (size_t)(N + 1) * 4;
    int* cur_m   = (int*)w;                  w += (size_t)(N + 1) * 4;
    int* cur_h   = (int*)w;                  w += (size_t)(N + 1) * 4;
    int* part_m  = (int*)w;                  w += 1024 * 4;
    int* part_h  = (int*)w;                  w += 1024 * 4;
    int* csr_src_m = (int*)w;                w += (size_t)E * 4;
    float* csr_w_m = (float*)w;              w += (size_t)E * 4;
    int* csr_src_h = (int*)w;                w += (size_t)E * 4;
    float* csr_w_h = (float*)w;              w += (size_t)E * 4;
    // split-bf16 weight fragments
    short* w1h = (short*)w;                  w += (size_t)KIN * 128 * 2;
    short* w1l = (short*)w;                  w += (size_t)KIN * 128 * 2;
    short* w2h = (short*)w;                  w += (size_t)128 * 128 * 2;
    short* w2l = (short*)w;                  w += (size_t)128 * 128 * 2;
    short* w3h = (short*)w;                  w += (size_t)128 * 128 * 2;
    short* w3l = (short*)w;                  w += (size_t)128 * 128 * 2;
    short* m1h = (short*)w;                  w += (size_t)128 * 128 * 2;
    short* m1l = (short*)w;                  w += (size_t)128 * 128 * 2;
    short* m2h = (short*)w;                  w += (size_t)128 * 128 * 2;
    short* m2l = (short*)w;                  w += (size_t)128 * 128 * 2;
    short* wdh = (short*)w;                  w += (size_t)128 * 128 * 2;
    short* wdl = (short*)w;                  w += (size_t)128 * 128 * 2;
    const size_t SLOT = (size_t)N * 128;
    float* S0 = (float*)w;                   w += SLOT * 4;
    float* S1 = (float*)w;                   w += SLOT * 4;
    float* S2 = (float*)w;                   w += SLOT * 4;
    float* S3 = (float*)w;                   w += SLOT * 4;
    float* sF = (float*)w;                   w += (size_t)N * 10 * 4;

    const int gN = (N + 255) / 256;
    const int gE = (E + 255) / 256;
    const int gGemmM = (N + 127) / 128;          // 782 blocks, 128 rows each
    const int gWave = (N * 64 + 255) / 256;
    const int gScore = (N + 3) / 4;
    const int gScan = (N + SCAN_CHUNK - 1) / SCAN_CHUNK;

    // ---- weight prep (independent of graph) ----
    k_wprep<<<(KIN * 128 + 255) / 256, 256, 0, stream>>>(W1, w1h, w1l, KIN);
    k_wprep<<<(128 * 128 + 255) / 256, 256, 0, stream>>>(W2, w2h, w2l, 128);
    k_wprep<<<(128 * 128 + 255) / 256, 256, 0, stream>>>(W3, w3h, w3l, 128);
    k_wprep<<<(128 * 128 + 255) / 256, 256, 0, stream>>>(M1, m1h, m1l, 128);
    k_wprep<<<(128 * 128 + 255) / 256, 256, 0, stream>>>(M2, m2h, m2l, 128);
    k_wprep<<<(128 * 128 + 255) / 256, 256, 0, stream>>>(Wd, wdh, wdl, 128);

    // ---- build CSR for both graphs ----
    k_zero2<<<gN, 256, 0, stream>>>(cnt_m, cnt_h, N);
    k_hist_int<<<gE, 256, 0, stream>>>(dst_m, cnt_m, E);
    k_hist_int<<<gE, 256, 0, stream>>>(dst_h, cnt_h, E);
    k_finalize<<<gN, 256, 0, stream>>>(cnt_m, dis_m, inv_m, N);
    k_finalize<<<gN, 256, 0, stream>>>(cnt_h, dis_h, inv_h, N);
    k_scan_partial<<<gScan, 256, 0, stream>>>(cnt_m, part_m, N);
    k_scan_partial<<<gScan, 256, 0, stream>>>(cnt_h, part_h, N);
    k_scan_part<<<1, 1024, 0, stream>>>(part_m, offs_m, cur_m, gScan, N);
    k_scan_part<<<1, 1024, 0, stream>>>(part_h, offs_h, cur_h, gScan, N);
    k_scan_final<<<gScan, 256, 0, stream>>>(cnt_m, part_m, offs_m, cur_m, N);
    k_scan_final<<<gScan, 256, 0, stream>>>(cnt_h, part_h, offs_h, cur_h, N);
    k_fill<<<gE, 256, 0, stream>>>(src_m, dst_m, dis_m, cur_m, csr_src_m, csr_w_m, E);
    k_fill<<<gE, 256, 0, stream>>>(src_h, dst_h, dis_h, cur_h, csr_src_h, csr_w_h, E);

    // ---- h1 = x @ W1 -> S0 (shared; bad branch via perm indirection) ----
    k_gemm_mfma<<<gGemmM, 256, 0, stream>>>(x, w1h, w1l, nullptr, S0, N, KIN, 0, 0);

    // agg1 -> S1 ; agg1b -> S2
    k_agg_gather<<<gWave, 256, 0, stream>>>(S1, S0, nullptr, offs_m, csr_src_m, csr_w_m, inv_m, b1, N);
    k_agg_gather<<<gWave, 256, 0, stream>>>(S2, S0, perm, offs_m, csr_src_m, csr_w_m, inv_m, b1, N);

    // h2 = relu(S1)@W2 -> S3 ; agg2 -> S1
    k_gemm_mfma<<<gGemmM, 256, 0, stream>>>(S1, w2h, w2l, nullptr, S3, N, 128, 1, 0);
    k_agg_gather<<<gWave, 256, 0, stream>>>(S1, S3, nullptr, offs_m, csr_src_m, csr_w_m, inv_m, b2, N);

    // h2b = relu(S2)@W2 -> S3 ; agg2b -> S2
    k_gemm_mfma<<<gGemmM, 256, 0, stream>>>(S2, w2h, w2l, nullptr, S3, N, 128, 1, 0);
    k_agg_gather<<<gWave, 256, 0, stream>>>(S2, S3, nullptr, offs_m, csr_src_m, csr_w_m, inv_m, b2, N);

    // h3 = relu(S1)@W3 -> S0 ; embed2 (hop graph) -> S3
    k_gemm_mfma<<<gGemmM, 256, 0, stream>>>(S1, w3h, w3l, nullptr, S0, N, 128, 1, 0);
    k_agg_gather<<<gWave, 256, 0, stream>>>(S3, S0, nullptr, offs_h, csr_src_h, csr_w_h, inv_h, b3, N);

    // classifier: hc = relu(S1)@Wc -> sF ; agg -> out cols 0..9
    k_gemm10<<<gN, 256, 0, stream>>>(S1, Wc, sF, N, 1);
    k_agg10_gather<<<gWave, 256, 0, stream>>>(out, sF, offs_m, csr_src_m, csr_w_m, inv_m, bc, N);

    // t = relu(relu(S1)@M1+mb1) -> S0 ; embed3 = S0@M2+mb2 -> S1
    k_gemm_mfma<<<gGemmM, 256, 0, stream>>>(S1, m1h, m1l, mb1, S0, N, 128, 1, 1);
    k_gemm_mfma<<<gGemmM, 256, 0, stream>>>(S0, m2h, m2l, mb2, S1, N, 128, 0, 0);

    // h3b = relu(S2)@W3 -> S0 ; embed2b -> S2
    k_gemm_mfma<<<gGemmM, 256, 0, stream>>>(S2, w3h, w3l, nullptr, S0, N, 128, 1, 0);
    k_agg_gather<<<gWave, 256, 0, stream>>>(S2, S0, nullptr, offs_h, csr_src_h, csr_w_h, inv_h, b3, N);

    // v = embed3(S1)@Wd -> S0 ; scores -> out cols 10,11
    k_gemm_mfma<<<gGemmM, 256, 0, stream>>>(S1, wdh, wdl, nullptr, S0, N, 128, 0, 0);
    k_score<<<gScore, 256, 0, stream>>>(S0, S3, S2, out, N);
}

// Round 5
// 1883.330 us; speedup vs baseline: 2.8480x; 1.1168x over previous
//
#include <hip/hip_runtime.h>
#include <cstddef>

#define NN 100000
#define NE 1600000
#define KIN 512
#define SCAN_CHUNK 1024

typedef __attribute__((ext_vector_type(8))) short bf16x8;   // 8 bf16 = 4 VGPR
typedef __attribute__((ext_vector_type(4))) float f32x4;

__device__ inline unsigned short f2bf_rne(float x) {
    unsigned int u = __float_as_uint(x);
    return (unsigned short)((u + 0x7fffu + ((u >> 16) & 1u)) >> 16);
}
__device__ inline float bf2f(unsigned short h) {
    return __uint_as_float(((unsigned int)h) << 16);
}

// ---------------- degree / CSR-build kernels ----------------
__global__ void k_zero2(int* __restrict__ a, int* __restrict__ b, int n) {
    int i = blockIdx.x * 256 + threadIdx.x;
    if (i < n) { a[i] = 0; b[i] = 0; }
}

__global__ void k_hist_int(const int* __restrict__ dst, int* __restrict__ cnt, int E) {
    int e = blockIdx.x * 256 + threadIdx.x;
    if (e < E) atomicAdd(&cnt[dst[e]], 1);
}

__global__ void k_finalize(const int* __restrict__ cnt, float* __restrict__ dis,
                           float* __restrict__ inv, int n) {
    int i = blockIdx.x * 256 + threadIdx.x;
    if (i < n) {
        float d = (float)cnt[i] + 1.0f;   // +1 self loop
        dis[i] = rsqrtf(d);
        inv[i] = 1.0f / d;
    }
}

// ---------------- 3-phase device-wide exclusive scan ----------------
__global__ __launch_bounds__(256) void k_scan_partial(const int* __restrict__ cnt,
                                                      int* __restrict__ part, int n) {
    __shared__ int red[256];
    int base = blockIdx.x * SCAN_CHUNK;
    int tid = threadIdx.x;
    int s = 0;
    for (int i = tid; i < SCAN_CHUNK; i += 256) {
        int g = base + i;
        if (g < n) s += cnt[g];
    }
    red[tid] = s;
    __syncthreads();
    for (int off = 128; off > 0; off >>= 1) {
        if (tid < off) red[tid] += red[tid + off];
        __syncthreads();
    }
    if (tid == 0) part[blockIdx.x] = red[0];
}

__global__ __launch_bounds__(1024) void k_scan_part(int* __restrict__ part,
                                                    int* __restrict__ offs,
                                                    int* __restrict__ cursor,
                                                    int B, int n) {
    __shared__ int s[1024];
    int tid = threadIdx.x;
    int v0 = (tid < B) ? part[tid] : 0;
    s[tid] = v0;
    __syncthreads();
    for (int off = 1; off < 1024; off <<= 1) {
        int v = (tid >= off) ? s[tid - off] : 0;
        __syncthreads();
        s[tid] += v;
        __syncthreads();
    }
    if (tid < B) part[tid] = s[tid] - v0;   // exclusive
    if (tid == B - 1) { offs[n] = s[tid]; cursor[n] = s[tid]; }
}

__global__ __launch_bounds__(256) void k_scan_final(const int* __restrict__ cnt,
                                                    const int* __restrict__ part,
                                                    int* __restrict__ offs,
                                                    int* __restrict__ cursor, int n) {
    __shared__ int tsum[256];
    int base = blockIdx.x * SCAN_CHUNK;
    int tid = threadIdx.x;
    int g0 = base + tid * 4;
    int c[4];
    int s = 0;
#pragma unroll
    for (int j = 0; j < 4; ++j) {
        int g = g0 + j;
        c[j] = (g < n) ? cnt[g] : 0;
        s += c[j];
    }
    tsum[tid] = s;
    __syncthreads();
    for (int off = 1; off < 256; off <<= 1) {
        int v = (tid >= off) ? tsum[tid - off] : 0;
        __syncthreads();
        tsum[tid] += v;
        __syncthreads();
    }
    int run = part[blockIdx.x] + tsum[tid] - s;
#pragma unroll
    for (int j = 0; j < 4; ++j) {
        int g = g0 + j;
        if (g < n) { offs[g] = run; cursor[g] = run; run += c[j]; }
    }
}

__global__ void k_fill(const int* __restrict__ src, const int* __restrict__ dst,
                       const float* __restrict__ dis, int* __restrict__ cursor,
                       int* __restrict__ csr_src, float* __restrict__ csr_w, int E) {
    int e = blockIdx.x * 256 + threadIdx.x;
    if (e >= E) return;
    int s = src[e], d = dst[e];
    int pos = atomicAdd(&cursor[d], 1);
    csr_src[pos] = s;
    csr_w[pos] = dis[s] * dis[d];
}

// ---------------- weight prep: fp32 [K x 128] -> split-bf16 B-fragment layout ----------------
__global__ void k_wprep(const float* __restrict__ W, short* __restrict__ hi,
                        short* __restrict__ lo, int K) {
    int idx = blockIdx.x * 256 + threadIdx.x;
    if (idx >= K * 128) return;
    int k = idx >> 7, n = idx & 127;
    float wv = W[idx];
    unsigned short h = f2bf_rne(wv);
    unsigned short l = f2bf_rne(wv - bf2f(h));
    int ktile = k >> 5, kk = k & 31;
    int c = kk >> 3, j = kk & 7;
    int ct = n >> 4, nn = n & 15;
    int lane = nn + 16 * c;
    size_t dst = (((size_t)ktile * 8 + ct) * 64 + lane) * 8 + j;
    hi[dst] = (short)h;
    lo[dst] = (short)l;
}

// ---------------- MFMA split-bf16 GEMM: C[M x 128] = op(A[M x K]) @ B[K x 128] ----------------
// LDS-free; A fp32 from global (split in-register), B preconverted frags (L2-broadcast).
// out_bf16: epilogue stores RNE-rounded bf16 (table feeds a gather), else fp32.
// In-place (C==A) is safe: each block reads only its own 128 rows before writing them.
__global__ __launch_bounds__(256) void k_gemm_mfma(
    const float* __restrict__ A, const short* __restrict__ Bh,
    const short* __restrict__ Bl, const float* __restrict__ bias,
    void* __restrict__ Cv, int M, int K, int relu_a, int relu_out, int out_bf16) {
    const int wave = threadIdx.x >> 6;
    const int lane = threadIdx.x & 63;
    const int mrow = lane & 15;
    const int kc = lane >> 4;           // 0..3 (k-chunk of 8)
    const int r0 = blockIdx.x * 128 + wave * 32;

    f32x4 acc[2][8];
#pragma unroll
    for (int t = 0; t < 2; ++t)
#pragma unroll
        for (int c = 0; c < 8; ++c) acc[t][c] = (f32x4){0.f, 0.f, 0.f, 0.f};

    const int ra0 = min(r0 + mrow, M - 1);
    const int ra1 = min(r0 + 16 + mrow, M - 1);
    const float* pa0 = A + (size_t)ra0 * K + 8 * kc;
    const float* pa1 = A + (size_t)ra1 * K + 8 * kc;

    const int nkt = K >> 5;
    for (int kt = 0; kt < nkt; ++kt) {
        float4 x00 = *(const float4*)(pa0 + kt * 32);
        float4 x01 = *(const float4*)(pa0 + kt * 32 + 4);
        float4 x10 = *(const float4*)(pa1 + kt * 32);
        float4 x11 = *(const float4*)(pa1 + kt * 32 + 4);
        float v0[8] = {x00.x, x00.y, x00.z, x00.w, x01.x, x01.y, x01.z, x01.w};
        float v1[8] = {x10.x, x10.y, x10.z, x10.w, x11.x, x11.y, x11.z, x11.w};
        if (relu_a) {
#pragma unroll
            for (int j = 0; j < 8; ++j) {
                v0[j] = fmaxf(v0[j], 0.f);
                v1[j] = fmaxf(v1[j], 0.f);
            }
        }
        bf16x8 ah0, al0, ah1, al1;
#pragma unroll
        for (int j = 0; j < 8; ++j) {
            unsigned int u0 = __float_as_uint(v0[j]);
            ah0[j] = (short)(u0 >> 16);
            float r0f = v0[j] - __uint_as_float(u0 & 0xffff0000u);
            al0[j] = (short)(__float_as_uint(r0f) >> 16);
            unsigned int u1 = __float_as_uint(v1[j]);
            ah1[j] = (short)(u1 >> 16);
            float r1f = v1[j] - __uint_as_float(u1 & 0xffff0000u);
            al1[j] = (short)(__float_as_uint(r1f) >> 16);
        }
        const short* bp = Bh + ((size_t)kt * 512 + lane) * 8;
        const short* lp = Bl + ((size_t)kt * 512 + lane) * 8;
#pragma unroll
        for (int ct = 0; ct < 8; ++ct) {
            bf16x8 bh = *(const bf16x8*)(bp + (size_t)ct * 512);
            bf16x8 bl = *(const bf16x8*)(lp + (size_t)ct * 512);
            acc[0][ct] = __builtin_amdgcn_mfma_f32_16x16x32_bf16(ah0, bh, acc[0][ct], 0, 0, 0);
            acc[0][ct] = __builtin_amdgcn_mfma_f32_16x16x32_bf16(al0, bh, acc[0][ct], 0, 0, 0);
            acc[0][ct] = __builtin_amdgcn_mfma_f32_16x16x32_bf16(ah0, bl, acc[0][ct], 0, 0, 0);
            acc[1][ct] = __builtin_amdgcn_mfma_f32_16x16x32_bf16(ah1, bh, acc[1][ct], 0, 0, 0);
            acc[1][ct] = __builtin_amdgcn_mfma_f32_16x16x32_bf16(al1, bh, acc[1][ct], 0, 0, 0);
            acc[1][ct] = __builtin_amdgcn_mfma_f32_16x16x32_bf16(ah1, bl, acc[1][ct], 0, 0, 0);
        }
    }

    float bv[8];
#pragma unroll
    for (int ct = 0; ct < 8; ++ct) bv[ct] = bias ? bias[ct * 16 + mrow] : 0.0f;
#pragma unroll
    for (int t = 0; t < 2; ++t) {
#pragma unroll
        for (int ct = 0; ct < 8; ++ct) {
#pragma unroll
            for (int r = 0; r < 4; ++r) {
                int row = r0 + 16 * t + kc * 4 + r;   // C/D: row=(lane>>4)*4+reg, col=lane&15
                if (row < M) {
                    float v = acc[t][ct][r] + bv[ct];
                    if (relu_out) v = fmaxf(v, 0.f);
                    size_t off = (size_t)row * 128 + ct * 16 + mrow;
                    if (out_bf16) ((unsigned short*)Cv)[off] = f2bf_rne(v);
                    else ((float*)Cv)[off] = v;
                }
            }
        }
    }
}

// ---------------- small GEMM: C[M x 10] = relu(A[M x 128]) @ W[128 x 10] ----------------
__global__ __launch_bounds__(256) void k_gemm10(
    const float* __restrict__ A, const float* __restrict__ W,
    float* __restrict__ C, int M, int relu_a) {
    __shared__ float Ws[128 * 10];
    int tid = threadIdx.x;
    for (int i = tid; i < 1280; i += 256) Ws[i] = W[i];
    __syncthreads();
    int row = blockIdx.x * 256 + tid;
    if (row >= M) return;
    float acc[10];
#pragma unroll
    for (int c = 0; c < 10; ++c) acc[c] = 0.0f;
    const float* a = A + (size_t)row * 128;
    for (int k = 0; k < 128; k += 4) {
        float4 av = *(const float4*)(a + k);
        if (relu_a) {
            av.x = fmaxf(av.x, 0.f); av.y = fmaxf(av.y, 0.f);
            av.z = fmaxf(av.z, 0.f); av.w = fmaxf(av.w, 0.f);
        }
        float vs[4] = {av.x, av.y, av.z, av.w};
#pragma unroll
        for (int j = 0; j < 4; ++j)
#pragma unroll
            for (int c = 0; c < 10; ++c)
                acc[c] = fmaf(vs[j], Ws[(k + j) * 10 + c], acc[c]);
    }
    float* o = C + (size_t)row * 10;
#pragma unroll
    for (int c = 0; c < 10; ++c) o[c] = acc[c];
}

// ---------------- GCN aggregation, CSR gather, bf16 h table (F=128) ----------------
// one wave per node; lane handles 2 feats (ushort2 = 4B). Output fp32.
__global__ __launch_bounds__(256) void k_agg_gather_bf16(
    float* __restrict__ out, const unsigned short* __restrict__ h,
    const int* __restrict__ permIdx,
    const int* __restrict__ offs, const int* __restrict__ csr_src,
    const float* __restrict__ csr_w,
    const float* __restrict__ inv, const float* __restrict__ bias, int n) {
    int gid = blockIdx.x * 256 + threadIdx.x;
    int node = gid >> 6;
    int lane = gid & 63;
    if (node >= n) return;
    const ushort2* h2 = (const ushort2*)h;
    int beg = offs[node], end = offs[node + 1];

    int sn = permIdx ? permIdx[node] : node;
    ushort2 hv = h2[(size_t)sn * 64 + lane];
    float2 bv = ((const float2*)bias)[lane];
    float iv = inv[node];
    float ax = fmaf(bf2f(hv.x), iv, bv.x);
    float ay = fmaf(bf2f(hv.y), iv, bv.y);

    for (int c = beg; c < end; c += 64) {
        int idx = c + lane;
        int s = 0; float w = 0.0f;
        if (idx < end) {
            s = csr_src[idx];
            w = csr_w[idx];
            if (permIdx) s = permIdx[s];
        }
        int cnt = min(64, end - c);
#pragma unroll 4
        for (int j = 0; j < cnt; ++j) {
            int sj = __shfl(s, j);
            float wj = __shfl(w, j);
            ushort2 hj = h2[(size_t)sj * 64 + lane];
            ax = fmaf(bf2f(hj.x), wj, ax);
            ay = fmaf(bf2f(hj.y), wj, ay);
        }
    }
    float2 o; o.x = ax; o.y = ay;
    ((float2*)out)[(size_t)node * 64 + lane] = o;
}

// ---------------- classifier aggregation gather (F=10, writes d_out stride 12) ----------------
__global__ __launch_bounds__(256) void k_agg10_gather(
    float* __restrict__ out, const float* __restrict__ hc,
    const int* __restrict__ offs, const int* __restrict__ csr_src,
    const float* __restrict__ csr_w,
    const float* __restrict__ inv, const float* __restrict__ bc, int n) {
    int gid = blockIdx.x * 256 + threadIdx.x;
    int node = gid >> 6;
    int lane = gid & 63;
    if (node >= n) return;
    int beg = offs[node], end = offs[node + 1];
    float acc = 0.0f;
    if (lane < 10) acc = fmaf(hc[(size_t)node * 10 + lane], inv[node], bc[lane]);
    for (int c = beg; c < end; c += 64) {
        int idx = c + lane;
        int s = 0; float w = 0.0f;
        if (idx < end) { s = csr_src[idx]; w = csr_w[idx]; }
        int cnt = min(64, end - c);
        for (int j = 0; j < cnt; ++j) {
            int sj = __shfl(s, j);
            float wj = __shfl(w, j);
            if (lane < 10) acc = fmaf(hc[(size_t)sj * 10 + lane], wj, acc);
        }
    }
    if (lane < 10) out[(size_t)node * 12 + lane] = acc;
}

// ---------------- bilinear scores ----------------
__global__ void k_score(const float* __restrict__ v, const float* __restrict__ e2,
                        const float* __restrict__ e2b, float* __restrict__ out, int n) {
    int tid = threadIdx.x;
    int node = blockIdx.x * 4 + (tid >> 6);
    int lane = tid & 63;
    if (node >= n) return;
    const float* vp = v + (size_t)node * 128;
    const float* ap = e2 + (size_t)node * 128;
    const float* bp = e2b + (size_t)node * 128;
    float v0 = vp[lane], v1 = vp[lane + 64];
    float s1 = v0 * ap[lane] + v1 * ap[lane + 64];
    float s2 = v0 * bp[lane] + v1 * bp[lane + 64];
#pragma unroll
    for (int off = 32; off > 0; off >>= 1) {
        s1 += __shfl_xor(s1, off);
        s2 += __shfl_xor(s2, off);
    }
    if (lane == 0) {
        out[(size_t)node * 12 + 10] = 1.0f / (1.0f + __expf(-s1));
        out[(size_t)node * 12 + 11] = 1.0f / (1.0f + __expf(-s2));
    }
}

extern "C" void kernel_launch(void* const* d_in, const int* in_sizes, int n_in,
                              void* d_out, int out_size, void* d_ws, size_t ws_size,
                              hipStream_t stream) {
    const float* x   = (const float*)d_in[0];
    const int*   ei  = (const int*)d_in[1];
    const int*   eih = (const int*)d_in[2];
    const int*   perm = (const int*)d_in[4];
    const float* W1 = (const float*)d_in[5];
    const float* b1 = (const float*)d_in[6];
    const float* W2 = (const float*)d_in[7];
    const float* b2 = (const float*)d_in[8];
    const float* W3 = (const float*)d_in[9];
    const float* b3 = (const float*)d_in[10];
    const float* M1 = (const float*)d_in[11];
    const float* mb1 = (const float*)d_in[12];
    const float* M2 = (const float*)d_in[13];
    const float* mb2 = (const float*)d_in[14];
    const float* Wc = (const float*)d_in[15];
    const float* bc = (const float*)d_in[16];
    const float* Wd = (const float*)d_in[17];
    float* out = (float*)d_out;

    const int N = NN, E = NE;
    const int* src_m = ei;
    const int* dst_m = ei + E;
    const int* src_h = eih;
    const int* dst_h = eih + E;

    // ---- workspace layout ----
    char* w = (char*)d_ws;
    float* dis_m = (float*)w;                w += (size_t)N * 4;
    float* inv_m = (float*)w;                w += (size_t)N * 4;
    float* dis_h = (float*)w;                w += (size_t)N * 4;
    float* inv_h = (float*)w;                w += (size_t)N * 4;
    int* cnt_m   = (int*)w;                  w += (size_t)N * 4;
    int* cnt_h   = (int*)w;                  w += (size_t)N * 4;
    int* offs_m  = (int*)w;                  w += (size_t)(N + 1) * 4;
    int* offs_h  = (int*)w;                  w += (size_t)(N + 1) * 4;
    int* cur_m   = (int*)w;                  w += (size_t)(N + 1) * 4;
    int* cur_h   = (int*)w;                  w += (size_t)(N + 1) * 4;
    int* part_m  = (int*)w;                  w += 1024 * 4;
    int* part_h  = (int*)w;                  w += 1024 * 4;
    int* csr_src_m = (int*)w;                w += (size_t)E * 4;
    float* csr_w_m = (float*)w;              w += (size_t)E * 4;
    int* csr_src_h = (int*)w;                w += (size_t)E * 4;
    float* csr_w_h = (float*)w;              w += (size_t)E * 4;
    // split-bf16 weight fragments
    short* w1h = (short*)w;                  w += (size_t)KIN * 128 * 2;
    short* w1l = (short*)w;                  w += (size_t)KIN * 128 * 2;
    short* w2h = (short*)w;                  w += (size_t)128 * 128 * 2;
    short* w2l = (short*)w;                  w += (size_t)128 * 128 * 2;
    short* w3h = (short*)w;                  w += (size_t)128 * 128 * 2;
    short* w3l = (short*)w;                  w += (size_t)128 * 128 * 2;
    short* m1h = (short*)w;                  w += (size_t)128 * 128 * 2;
    short* m1l = (short*)w;                  w += (size_t)128 * 128 * 2;
    short* m2h = (short*)w;                  w += (size_t)128 * 128 * 2;
    short* m2l = (short*)w;                  w += (size_t)128 * 128 * 2;
    short* wdh = (short*)w;                  w += (size_t)128 * 128 * 2;
    short* wdl = (short*)w;                  w += (size_t)128 * 128 * 2;
    const size_t SLOT = (size_t)N * 128;
    unsigned short* Hb = (unsigned short*)w; w += SLOT * 2;      // shared bf16 h table
    float* S1 = (float*)w;                   w += SLOT * 4;
    float* S2 = (float*)w;                   w += SLOT * 4;
    float* S3 = (float*)w;                   w += SLOT * 4;
    float* sF = (float*)w;                   w += (size_t)N * 10 * 4;

    const int gN = (N + 255) / 256;
    const int gE = (E + 255) / 256;
    const int gGemmM = (N + 127) / 128;
    const int gWave = (N * 64 + 255) / 256;
    const int gScore = (N + 3) / 4;
    const int gScan = (N + SCAN_CHUNK - 1) / SCAN_CHUNK;

    // ---- weight prep ----
    k_wprep<<<(KIN * 128 + 255) / 256, 256, 0, stream>>>(W1, w1h, w1l, KIN);
    k_wprep<<<(128 * 128 + 255) / 256, 256, 0, stream>>>(W2, w2h, w2l, 128);
    k_wprep<<<(128 * 128 + 255) / 256, 256, 0, stream>>>(W3, w3h, w3l, 128);
    k_wprep<<<(128 * 128 + 255) / 256, 256, 0, stream>>>(M1, m1h, m1l, 128);
    k_wprep<<<(128 * 128 + 255) / 256, 256, 0, stream>>>(M2, m2h, m2l, 128);
    k_wprep<<<(128 * 128 + 255) / 256, 256, 0, stream>>>(Wd, wdh, wdl, 128);

    // ---- build CSR for both graphs ----
    k_zero2<<<gN, 256, 0, stream>>>(cnt_m, cnt_h, N);
    k_hist_int<<<gE, 256, 0, stream>>>(dst_m, cnt_m, E);
    k_hist_int<<<gE, 256, 0, stream>>>(dst_h, cnt_h, E);
    k_finalize<<<gN, 256, 0, stream>>>(cnt_m, dis_m, inv_m, N);
    k_finalize<<<gN, 256, 0, stream>>>(cnt_h, dis_h, inv_h, N);
    k_scan_partial<<<gScan, 256, 0, stream>>>(cnt_m, part_m, N);
    k_scan_partial<<<gScan, 256, 0, stream>>>(cnt_h, part_h, N);
    k_scan_part<<<1, 1024, 0, stream>>>(part_m, offs_m, cur_m, gScan, N);
    k_scan_part<<<1, 1024, 0, stream>>>(part_h, offs_h, cur_h, gScan, N);
    k_scan_final<<<gScan, 256, 0, stream>>>(cnt_m, part_m, offs_m, cur_m, N);
    k_scan_final<<<gScan, 256, 0, stream>>>(cnt_h, part_h, offs_h, cur_h, N);
    k_fill<<<gE, 256, 0, stream>>>(src_m, dst_m, dis_m, cur_m, csr_src_m, csr_w_m, E);
    k_fill<<<gE, 256, 0, stream>>>(src_h, dst_h, dis_h, cur_h, csr_src_h, csr_w_h, E);

    // ---- h1 = x @ W1 -> Hb (bf16) ----
    k_gemm_mfma<<<gGemmM, 256, 0, stream>>>(x, w1h, w1l, nullptr, Hb, N, KIN, 0, 0, 1);
    // agg1 -> S1 ; agg1b (perm) -> S2
    k_agg_gather_bf16<<<gWave, 256, 0, stream>>>(S1, Hb, nullptr, offs_m, csr_src_m, csr_w_m, inv_m, b1, N);
    k_agg_gather_bf16<<<gWave, 256, 0, stream>>>(S2, Hb, perm, offs_m, csr_src_m, csr_w_m, inv_m, b1, N);

    // h2 = relu(S1)@W2 -> Hb ; agg2 -> S1
    k_gemm_mfma<<<gGemmM, 256, 0, stream>>>(S1, w2h, w2l, nullptr, Hb, N, 128, 1, 0, 1);
    k_agg_gather_bf16<<<gWave, 256, 0, stream>>>(S1, Hb, nullptr, offs_m, csr_src_m, csr_w_m, inv_m, b2, N);
    // h2b = relu(S2)@W2 -> Hb ; agg2b -> S2
    k_gemm_mfma<<<gGemmM, 256, 0, stream>>>(S2, w2h, w2l, nullptr, Hb, N, 128, 1, 0, 1);
    k_agg_gather_bf16<<<gWave, 256, 0, stream>>>(S2, Hb, nullptr, offs_m, csr_src_m, csr_w_m, inv_m, b2, N);

    // h3 = relu(S1)@W3 -> Hb ; embed2 (hop) -> S3
    k_gemm_mfma<<<gGemmM, 256, 0, stream>>>(S1, w3h, w3l, nullptr, Hb, N, 128, 1, 0, 1);
    k_agg_gather_bf16<<<gWave, 256, 0, stream>>>(S3, Hb, nullptr, offs_h, csr_src_h, csr_w_h, inv_h, b3, N);
    // h3b = relu(S2)@W3 -> Hb ; embed2b -> S2 (G3b finished reading S2 first)
    k_gemm_mfma<<<gGemmM, 256, 0, stream>>>(S2, w3h, w3l, nullptr, Hb, N, 128, 1, 0, 1);
    k_agg_gather_bf16<<<gWave, 256, 0, stream>>>(S2, Hb, nullptr, offs_h, csr_src_h, csr_w_h, inv_h, b3, N);

    // classifier: hc = relu(S1)@Wc -> sF ; agg -> out cols 0..9
    k_gemm10<<<gN, 256, 0, stream>>>(S1, Wc, sF, N, 1);
    k_agg10_gather<<<gWave, 256, 0, stream>>>(out, sF, offs_m, csr_src_m, csr_w_m, inv_m, bc, N);

    // MLP chain, in-place on S1: t = relu(relu(a2)@M1+mb1); e3 = t@M2+mb2; v = e3@Wd
    k_gemm_mfma<<<gGemmM, 256, 0, stream>>>(S1, m1h, m1l, mb1, S1, N, 128, 1, 1, 0);
    k_gemm_mfma<<<gGemmM, 256, 0, stream>>>(S1, m2h, m2l, mb2, S1, N, 128, 0, 0, 0);
    k_gemm_mfma<<<gGemmM, 256, 0, stream>>>(S1, wdh, wdl, nullptr, S1, N, 128, 0, 0, 0);

    // scores -> out cols 10,11
    k_score<<<gScore, 256, 0, stream>>>(S1, S3, S2, out, N);
}

// Round 6
// 1821.798 us; speedup vs baseline: 2.9442x; 1.0338x over previous
//
#include <hip/hip_runtime.h>
#include <cstddef>

#define NN 100000
#define NE 1600000
#define KIN 512
#define SCAN_CHUNK 1024

typedef __attribute__((ext_vector_type(8))) short bf16x8;   // 8 bf16 = 4 VGPR
typedef __attribute__((ext_vector_type(4))) float f32x4;

__device__ inline unsigned short f2bf_rne(float x) {
    unsigned int u = __float_as_uint(x);
    return (unsigned short)((u + 0x7fffu + ((u >> 16) & 1u)) >> 16);
}
__device__ inline float bf2f(unsigned short h) {
    return __uint_as_float(((unsigned int)h) << 16);
}

// ---------------- degree / CSR-build kernels ----------------
__global__ void k_zero2(int* __restrict__ a, int* __restrict__ b, int n) {
    int i = blockIdx.x * 256 + threadIdx.x;
    if (i < n) { a[i] = 0; b[i] = 0; }
}

__global__ void k_hist_int(const int* __restrict__ dst, int* __restrict__ cnt, int E) {
    int e = blockIdx.x * 256 + threadIdx.x;
    if (e < E) atomicAdd(&cnt[dst[e]], 1);
}

__global__ void k_finalize(const int* __restrict__ cnt, float* __restrict__ dis,
                           float* __restrict__ inv, int n) {
    int i = blockIdx.x * 256 + threadIdx.x;
    if (i < n) {
        float d = (float)cnt[i] + 1.0f;   // +1 self loop
        dis[i] = rsqrtf(d);
        inv[i] = 1.0f / d;
    }
}

// ---------------- 3-phase device-wide exclusive scan ----------------
__global__ __launch_bounds__(256) void k_scan_partial(const int* __restrict__ cnt,
                                                      int* __restrict__ part, int n) {
    __shared__ int red[256];
    int base = blockIdx.x * SCAN_CHUNK;
    int tid = threadIdx.x;
    int s = 0;
    for (int i = tid; i < SCAN_CHUNK; i += 256) {
        int g = base + i;
        if (g < n) s += cnt[g];
    }
    red[tid] = s;
    __syncthreads();
    for (int off = 128; off > 0; off >>= 1) {
        if (tid < off) red[tid] += red[tid + off];
        __syncthreads();
    }
    if (tid == 0) part[blockIdx.x] = red[0];
}

__global__ __launch_bounds__(1024) void k_scan_part(int* __restrict__ part,
                                                    int* __restrict__ offs,
                                                    int* __restrict__ cursor,
                                                    int B, int n) {
    __shared__ int s[1024];
    int tid = threadIdx.x;
    int v0 = (tid < B) ? part[tid] : 0;
    s[tid] = v0;
    __syncthreads();
    for (int off = 1; off < 1024; off <<= 1) {
        int v = (tid >= off) ? s[tid - off] : 0;
        __syncthreads();
        s[tid] += v;
        __syncthreads();
    }
    if (tid < B) part[tid] = s[tid] - v0;   // exclusive
    if (tid == B - 1) { offs[n] = s[tid]; cursor[n] = s[tid]; }
}

__global__ __launch_bounds__(256) void k_scan_final(const int* __restrict__ cnt,
                                                    const int* __restrict__ part,
                                                    int* __restrict__ offs,
                                                    int* __restrict__ cursor, int n) {
    __shared__ int tsum[256];
    int base = blockIdx.x * SCAN_CHUNK;
    int tid = threadIdx.x;
    int g0 = base + tid * 4;
    int c[4];
    int s = 0;
#pragma unroll
    for (int j = 0; j < 4; ++j) {
        int g = g0 + j;
        c[j] = (g < n) ? cnt[g] : 0;
        s += c[j];
    }
    tsum[tid] = s;
    __syncthreads();
    for (int off = 1; off < 256; off <<= 1) {
        int v = (tid >= off) ? tsum[tid - off] : 0;
        __syncthreads();
        tsum[tid] += v;
        __syncthreads();
    }
    int run = part[blockIdx.x] + tsum[tid] - s;
#pragma unroll
    for (int j = 0; j < 4; ++j) {
        int g = g0 + j;
        if (g < n) { offs[g] = run; cursor[g] = run; run += c[j]; }
    }
}

__global__ void k_fill(const int* __restrict__ src, const int* __restrict__ dst,
                       const float* __restrict__ dis, int* __restrict__ cursor,
                       int* __restrict__ csr_src, float* __restrict__ csr_w, int E) {
    int e = blockIdx.x * 256 + threadIdx.x;
    if (e >= E) return;
    int s = src[e], d = dst[e];
    int pos = atomicAdd(&cursor[d], 1);
    csr_src[pos] = s;
    csr_w[pos] = dis[s] * dis[d];
}

// ---------------- weight prep: fp32 [K x 128] -> split-bf16 B-fragment layout ----------------
// short index: ktile*4096 + ct*512 + lane*8 + j  (ktile = k/32)
__global__ void k_wprep(const float* __restrict__ W, short* __restrict__ hi,
                        short* __restrict__ lo, int K) {
    int idx = blockIdx.x * 256 + threadIdx.x;
    if (idx >= K * 128) return;
    int k = idx >> 7, n = idx & 127;
    float wv = W[idx];
    unsigned short h = f2bf_rne(wv);
    unsigned short l = f2bf_rne(wv - bf2f(h));
    int ktile = k >> 5, kk = k & 31;
    int c = kk >> 3, j = kk & 7;
    int ct = n >> 4, nn = n & 15;
    int lane = nn + 16 * c;
    size_t dst = (((size_t)ktile * 8 + ct) * 64 + lane) * 8 + j;
    hi[dst] = (short)h;
    lo[dst] = (short)l;
}

// ---------------- MFMA split-bf16 GEMM: C[M x 128] = op(A[M x K]) @ B[K x 128] ----------------
// B fragments staged in LDS per 128-K chunk (kills L2 thrash / HBM refetch of B).
// A fp32 from global (split in-register). In-place (C==A) safe: block reads only own rows.
__global__ __launch_bounds__(256) void k_gemm_mfma(
    const float* __restrict__ A, const short* __restrict__ Bh,
    const short* __restrict__ Bl, const float* __restrict__ bias,
    void* __restrict__ Cv, int M, int K, int relu_a, int relu_out, int out_bf16) {
    __shared__ __align__(16) short lBh[16384];   // 32 KB: 4 ktiles x 8 ct x 64 lanes x 8
    __shared__ __align__(16) short lBl[16384];   // 32 KB

    const int tid = threadIdx.x;
    const int wave = tid >> 6;
    const int lane = tid & 63;
    const int mrow = lane & 15;
    const int kc = lane >> 4;           // 0..3 (k-chunk of 8)
    const int r0 = blockIdx.x * 128 + wave * 32;

    f32x4 acc[2][8];
#pragma unroll
    for (int t = 0; t < 2; ++t)
#pragma unroll
        for (int c = 0; c < 8; ++c) acc[t][c] = (f32x4){0.f, 0.f, 0.f, 0.f};

    const int ra0 = min(r0 + mrow, M - 1);
    const int ra1 = min(r0 + 16 + mrow, M - 1);
    const float* pa0 = A + (size_t)ra0 * K + 8 * kc;
    const float* pa1 = A + (size_t)ra1 * K + 8 * kc;

    for (int kc0 = 0; kc0 < K; kc0 += 128) {
        // ---- stage this 128-K chunk of B frags into LDS (coalesced int4) ----
        {
            const int4* gh = (const int4*)(Bh + (size_t)(kc0 >> 5) * 4096);
            const int4* gl = (const int4*)(Bl + (size_t)(kc0 >> 5) * 4096);
            int4* sh = (int4*)lBh;
            int4* sl = (int4*)lBl;
#pragma unroll
            for (int i = 0; i < 8; ++i) {
                sh[tid + i * 256] = gh[tid + i * 256];
                sl[tid + i * 256] = gl[tid + i * 256];
            }
        }
        __syncthreads();

#pragma unroll
        for (int kt = 0; kt < 4; ++kt) {
            const float* q0 = pa0 + kc0 + kt * 32;
            const float* q1 = pa1 + kc0 + kt * 32;
            float4 x00 = *(const float4*)(q0);
            float4 x01 = *(const float4*)(q0 + 4);
            float4 x10 = *(const float4*)(q1);
            float4 x11 = *(const float4*)(q1 + 4);
            float v0[8] = {x00.x, x00.y, x00.z, x00.w, x01.x, x01.y, x01.z, x01.w};
            float v1[8] = {x10.x, x10.y, x10.z, x10.w, x11.x, x11.y, x11.z, x11.w};
            if (relu_a) {
#pragma unroll
                for (int j = 0; j < 8; ++j) {
                    v0[j] = fmaxf(v0[j], 0.f);
                    v1[j] = fmaxf(v1[j], 0.f);
                }
            }
            bf16x8 ah0, al0, ah1, al1;
#pragma unroll
            for (int j = 0; j < 8; ++j) {
                unsigned int u0 = __float_as_uint(v0[j]);
                ah0[j] = (short)(u0 >> 16);
                float r0f = v0[j] - __uint_as_float(u0 & 0xffff0000u);
                al0[j] = (short)(__float_as_uint(r0f) >> 16);
                unsigned int u1 = __float_as_uint(v1[j]);
                ah1[j] = (short)(u1 >> 16);
                float r1f = v1[j] - __uint_as_float(u1 & 0xffff0000u);
                al1[j] = (short)(__float_as_uint(r1f) >> 16);
            }
            const int bbase = kt * 4096 + lane * 8;
#pragma unroll
            for (int ct = 0; ct < 8; ++ct) {
                bf16x8 bh = *(const bf16x8*)&lBh[bbase + ct * 512];
                bf16x8 bl = *(const bf16x8*)&lBl[bbase + ct * 512];
                acc[0][ct] = __builtin_amdgcn_mfma_f32_16x16x32_bf16(ah0, bh, acc[0][ct], 0, 0, 0);
                acc[0][ct] = __builtin_amdgcn_mfma_f32_16x16x32_bf16(al0, bh, acc[0][ct], 0, 0, 0);
                acc[0][ct] = __builtin_amdgcn_mfma_f32_16x16x32_bf16(ah0, bl, acc[0][ct], 0, 0, 0);
                acc[1][ct] = __builtin_amdgcn_mfma_f32_16x16x32_bf16(ah1, bh, acc[1][ct], 0, 0, 0);
                acc[1][ct] = __builtin_amdgcn_mfma_f32_16x16x32_bf16(al1, bh, acc[1][ct], 0, 0, 0);
                acc[1][ct] = __builtin_amdgcn_mfma_f32_16x16x32_bf16(ah1, bl, acc[1][ct], 0, 0, 0);
            }
        }
        __syncthreads();
    }

    float bv[8];
#pragma unroll
    for (int ct = 0; ct < 8; ++ct) bv[ct] = bias ? bias[ct * 16 + mrow] : 0.0f;
#pragma unroll
    for (int t = 0; t < 2; ++t) {
#pragma unroll
        for (int ct = 0; ct < 8; ++ct) {
#pragma unroll
            for (int r = 0; r < 4; ++r) {
                int row = r0 + 16 * t + kc * 4 + r;   // C/D: row=(lane>>4)*4+reg, col=lane&15
                if (row < M) {
                    float v = acc[t][ct][r] + bv[ct];
                    if (relu_out) v = fmaxf(v, 0.f);
                    size_t off = (size_t)row * 128 + ct * 16 + mrow;
                    if (out_bf16) ((unsigned short*)Cv)[off] = f2bf_rne(v);
                    else ((float*)Cv)[off] = v;
                }
            }
        }
    }
}

// ---------------- small GEMM: C[M x 10] = relu(A[M x 128]) @ W[128 x 10] ----------------
__global__ __launch_bounds__(256) void k_gemm10(
    const float* __restrict__ A, const float* __restrict__ W,
    float* __restrict__ C, int M, int relu_a) {
    __shared__ float Ws[128 * 10];
    int tid = threadIdx.x;
    for (int i = tid; i < 1280; i += 256) Ws[i] = W[i];
    __syncthreads();
    int row = blockIdx.x * 256 + tid;
    if (row >= M) return;
    float acc[10];
#pragma unroll
    for (int c = 0; c < 10; ++c) acc[c] = 0.0f;
    const float* a = A + (size_t)row * 128;
    for (int k = 0; k < 128; k += 4) {
        float4 av = *(const float4*)(a + k);
        if (relu_a) {
            av.x = fmaxf(av.x, 0.f); av.y = fmaxf(av.y, 0.f);
            av.z = fmaxf(av.z, 0.f); av.w = fmaxf(av.w, 0.f);
        }
        float vs[4] = {av.x, av.y, av.z, av.w};
#pragma unroll
        for (int j = 0; j < 4; ++j)
#pragma unroll
            for (int c = 0; c < 10; ++c)
                acc[c] = fmaf(vs[j], Ws[(k + j) * 10 + c], acc[c]);
    }
    float* o = C + (size_t)row * 10;
#pragma unroll
    for (int c = 0; c < 10; ++c) o[c] = acc[c];
}

// ---------------- GCN aggregation, CSR gather, bf16 h table (F=128) ----------------
__global__ __launch_bounds__(256) void k_agg_gather_bf16(
    float* __restrict__ out, const unsigned short* __restrict__ h,
    const int* __restrict__ permIdx,
    const int* __restrict__ offs, const int* __restrict__ csr_src,
    const float* __restrict__ csr_w,
    const float* __restrict__ inv, const float* __restrict__ bias, int n) {
    int gid = blockIdx.x * 256 + threadIdx.x;
    int node = gid >> 6;
    int lane = gid & 63;
    if (node >= n) return;
    const ushort2* h2 = (const ushort2*)h;
    int beg = offs[node], end = offs[node + 1];

    int sn = permIdx ? permIdx[node] : node;
    ushort2 hv = h2[(size_t)sn * 64 + lane];
    float2 bv = ((const float2*)bias)[lane];
    float iv = inv[node];
    float ax = fmaf(bf2f(hv.x), iv, bv.x);
    float ay = fmaf(bf2f(hv.y), iv, bv.y);

    for (int c = beg; c < end; c += 64) {
        int idx = c + lane;
        int s = 0; float w = 0.0f;
        if (idx < end) {
            s = csr_src[idx];
            w = csr_w[idx];
            if (permIdx) s = permIdx[s];
        }
        int cnt = min(64, end - c);
#pragma unroll 4
        for (int j = 0; j < cnt; ++j) {
            int sj = __shfl(s, j);
            float wj = __shfl(w, j);
            ushort2 hj = h2[(size_t)sj * 64 + lane];
            ax = fmaf(bf2f(hj.x), wj, ax);
            ay = fmaf(bf2f(hj.y), wj, ay);
        }
    }
    float2 o; o.x = ax; o.y = ay;
    ((float2*)out)[(size_t)node * 64 + lane] = o;
}

// ---------------- classifier aggregation gather (F=10, writes d_out stride 12) ----------------
__global__ __launch_bounds__(256) void k_agg10_gather(
    float* __restrict__ out, const float* __restrict__ hc,
    const int* __restrict__ offs, const int* __restrict__ csr_src,
    const float* __restrict__ csr_w,
    const float* __restrict__ inv, const float* __restrict__ bc, int n) {
    int gid = blockIdx.x * 256 + threadIdx.x;
    int node = gid >> 6;
    int lane = gid & 63;
    if (node >= n) return;
    int beg = offs[node], end = offs[node + 1];
    float acc = 0.0f;
    if (lane < 10) acc = fmaf(hc[(size_t)node * 10 + lane], inv[node], bc[lane]);
    for (int c = beg; c < end; c += 64) {
        int idx = c + lane;
        int s = 0; float w = 0.0f;
        if (idx < end) { s = csr_src[idx]; w = csr_w[idx]; }
        int cnt = min(64, end - c);
        for (int j = 0; j < cnt; ++j) {
            int sj = __shfl(s, j);
            float wj = __shfl(w, j);
            if (lane < 10) acc = fmaf(hc[(size_t)sj * 10 + lane], wj, acc);
        }
    }
    if (lane < 10) out[(size_t)node * 12 + lane] = acc;
}

// ---------------- bilinear scores ----------------
__global__ void k_score(const float* __restrict__ v, const float* __restrict__ e2,
                        const float* __restrict__ e2b, float* __restrict__ out, int n) {
    int tid = threadIdx.x;
    int node = blockIdx.x * 4 + (tid >> 6);
    int lane = tid & 63;
    if (node >= n) return;
    const float* vp = v + (size_t)node * 128;
    const float* ap = e2 + (size_t)node * 128;
    const float* bp = e2b + (size_t)node * 128;
    float v0 = vp[lane], v1 = vp[lane + 64];
    float s1 = v0 * ap[lane] + v1 * ap[lane + 64];
    float s2 = v0 * bp[lane] + v1 * bp[lane + 64];
#pragma unroll
    for (int off = 32; off > 0; off >>= 1) {
        s1 += __shfl_xor(s1, off);
        s2 += __shfl_xor(s2, off);
    }
    if (lane == 0) {
        out[(size_t)node * 12 + 10] = 1.0f / (1.0f + __expf(-s1));
        out[(size_t)node * 12 + 11] = 1.0f / (1.0f + __expf(-s2));
    }
}

extern "C" void kernel_launch(void* const* d_in, const int* in_sizes, int n_in,
                              void* d_out, int out_size, void* d_ws, size_t ws_size,
                              hipStream_t stream) {
    const float* x   = (const float*)d_in[0];
    const int*   ei  = (const int*)d_in[1];
    const int*   eih = (const int*)d_in[2];
    const int*   perm = (const int*)d_in[4];
    const float* W1 = (const float*)d_in[5];
    const float* b1 = (const float*)d_in[6];
    const float* W2 = (const float*)d_in[7];
    const float* b2 = (const float*)d_in[8];
    const float* W3 = (const float*)d_in[9];
    const float* b3 = (const float*)d_in[10];
    const float* M1 = (const float*)d_in[11];
    const float* mb1 = (const float*)d_in[12];
    const float* M2 = (const float*)d_in[13];
    const float* mb2 = (const float*)d_in[14];
    const float* Wc = (const float*)d_in[15];
    const float* bc = (const float*)d_in[16];
    const float* Wd = (const float*)d_in[17];
    float* out = (float*)d_out;

    const int N = NN, E = NE;
    const int* src_m = ei;
    const int* dst_m = ei + E;
    const int* src_h = eih;
    const int* dst_h = eih + E;

    // ---- workspace layout ----
    char* w = (char*)d_ws;
    float* dis_m = (float*)w;                w += (size_t)N * 4;
    float* inv_m = (float*)w;                w += (size_t)N * 4;
    float* dis_h = (float*)w;                w += (size_t)N * 4;
    float* inv_h = (float*)w;                w += (size_t)N * 4;
    int* cnt_m   = (int*)w;                  w += (size_t)N * 4;
    int* cnt_h   = (int*)w;                  w += (size_t)N * 4;
    int* offs_m  = (int*)w;                  w += (size_t)(N + 1) * 4;
    int* offs_h  = (int*)w;                  w += (size_t)(N + 1) * 4;
    int* cur_m   = (int*)w;                  w += (size_t)(N + 1) * 4;
    int* cur_h   = (int*)w;                  w += (size_t)(N + 1) * 4;
    int* part_m  = (int*)w;                  w += 1024 * 4;
    int* part_h  = (int*)w;                  w += 1024 * 4;
    int* csr_src_m = (int*)w;                w += (size_t)E * 4;
    float* csr_w_m = (float*)w;              w += (size_t)E * 4;
    int* csr_src_h = (int*)w;                w += (size_t)E * 4;
    float* csr_w_h = (float*)w;              w += (size_t)E * 4;
    // split-bf16 weight fragments
    short* w1h = (short*)w;                  w += (size_t)KIN * 128 * 2;
    short* w1l = (short*)w;                  w += (size_t)KIN * 128 * 2;
    short* w2h = (short*)w;                  w += (size_t)128 * 128 * 2;
    short* w2l = (short*)w;                  w += (size_t)128 * 128 * 2;
    short* w3h = (short*)w;                  w += (size_t)128 * 128 * 2;
    short* w3l = (short*)w;                  w += (size_t)128 * 128 * 2;
    short* m1h = (short*)w;                  w += (size_t)128 * 128 * 2;
    short* m1l = (short*)w;                  w += (size_t)128 * 128 * 2;
    short* m2h = (short*)w;                  w += (size_t)128 * 128 * 2;
    short* m2l = (short*)w;                  w += (size_t)128 * 128 * 2;
    short* wdh = (short*)w;                  w += (size_t)128 * 128 * 2;
    short* wdl = (short*)w;                  w += (size_t)128 * 128 * 2;
    const size_t SLOT = (size_t)N * 128;
    unsigned short* Hb = (unsigned short*)w; w += SLOT * 2;      // shared bf16 h table
    float* S1 = (float*)w;                   w += SLOT * 4;
    float* S2 = (float*)w;                   w += SLOT * 4;
    float* S3 = (float*)w;                   w += SLOT * 4;
    float* sF = (float*)w;                   w += (size_t)N * 10 * 4;

    const int gN = (N + 255) / 256;
    const int gE = (E + 255) / 256;
    const int gGemmM = (N + 127) / 128;
    const int gWave = (N * 64 + 255) / 256;
    const int gScore = (N + 3) / 4;
    const int gScan = (N + SCAN_CHUNK - 1) / SCAN_CHUNK;

    // ---- weight prep ----
    k_wprep<<<(KIN * 128 + 255) / 256, 256, 0, stream>>>(W1, w1h, w1l, KIN);
    k_wprep<<<(128 * 128 + 255) / 256, 256, 0, stream>>>(W2, w2h, w2l, 128);
    k_wprep<<<(128 * 128 + 255) / 256, 256, 0, stream>>>(W3, w3h, w3l, 128);
    k_wprep<<<(128 * 128 + 255) / 256, 256, 0, stream>>>(M1, m1h, m1l, 128);
    k_wprep<<<(128 * 128 + 255) / 256, 256, 0, stream>>>(M2, m2h, m2l, 128);
    k_wprep<<<(128 * 128 + 255) / 256, 256, 0, stream>>>(Wd, wdh, wdl, 128);

    // ---- build CSR for both graphs ----
    k_zero2<<<gN, 256, 0, stream>>>(cnt_m, cnt_h, N);
    k_hist_int<<<gE, 256, 0, stream>>>(dst_m, cnt_m, E);
    k_hist_int<<<gE, 256, 0, stream>>>(dst_h, cnt_h, E);
    k_finalize<<<gN, 256, 0, stream>>>(cnt_m, dis_m, inv_m, N);
    k_finalize<<<gN, 256, 0, stream>>>(cnt_h, dis_h, inv_h, N);
    k_scan_partial<<<gScan, 256, 0, stream>>>(cnt_m, part_m, N);
    k_scan_partial<<<gScan, 256, 0, stream>>>(cnt_h, part_h, N);
    k_scan_part<<<1, 1024, 0, stream>>>(part_m, offs_m, cur_m, gScan, N);
    k_scan_part<<<1, 1024, 0, stream>>>(part_h, offs_h, cur_h, gScan, N);
    k_scan_final<<<gScan, 256, 0, stream>>>(cnt_m, part_m, offs_m, cur_m, N);
    k_scan_final<<<gScan, 256, 0, stream>>>(cnt_h, part_h, offs_h, cur_h, N);
    k_fill<<<gE, 256, 0, stream>>>(src_m, dst_m, dis_m, cur_m, csr_src_m, csr_w_m, E);
    k_fill<<<gE, 256, 0, stream>>>(src_h, dst_h, dis_h, cur_h, csr_src_h, csr_w_h, E);

    // ---- h1 = x @ W1 -> Hb (bf16) ----
    k_gemm_mfma<<<gGemmM, 256, 0, stream>>>(x, w1h, w1l, nullptr, Hb, N, KIN, 0, 0, 1);
    // agg1 -> S1 ; agg1b (perm) -> S2
    k_agg_gather_bf16<<<gWave, 256, 0, stream>>>(S1, Hb, nullptr, offs_m, csr_src_m, csr_w_m, inv_m, b1, N);
    k_agg_gather_bf16<<<gWave, 256, 0, stream>>>(S2, Hb, perm, offs_m, csr_src_m, csr_w_m, inv_m, b1, N);

    // h2 = relu(S1)@W2 -> Hb ; agg2 -> S1
    k_gemm_mfma<<<gGemmM, 256, 0, stream>>>(S1, w2h, w2l, nullptr, Hb, N, 128, 1, 0, 1);
    k_agg_gather_bf16<<<gWave, 256, 0, stream>>>(S1, Hb, nullptr, offs_m, csr_src_m, csr_w_m, inv_m, b2, N);
    // h2b = relu(S2)@W2 -> Hb ; agg2b -> S2
    k_gemm_mfma<<<gGemmM, 256, 0, stream>>>(S2, w2h, w2l, nullptr, Hb, N, 128, 1, 0, 1);
    k_agg_gather_bf16<<<gWave, 256, 0, stream>>>(S2, Hb, nullptr, offs_m, csr_src_m, csr_w_m, inv_m, b2, N);

    // h3 = relu(S1)@W3 -> Hb ; embed2 (hop) -> S3
    k_gemm_mfma<<<gGemmM, 256, 0, stream>>>(S1, w3h, w3l, nullptr, Hb, N, 128, 1, 0, 1);
    k_agg_gather_bf16<<<gWave, 256, 0, stream>>>(S3, Hb, nullptr, offs_h, csr_src_h, csr_w_h, inv_h, b3, N);
    // h3b = relu(S2)@W3 -> Hb ; embed2b -> S2
    k_gemm_mfma<<<gGemmM, 256, 0, stream>>>(S2, w3h, w3l, nullptr, Hb, N, 128, 1, 0, 1);
    k_agg_gather_bf16<<<gWave, 256, 0, stream>>>(S2, Hb, nullptr, offs_h, csr_src_h, csr_w_h, inv_h, b3, N);

    // classifier: hc = relu(S1)@Wc -> sF ; agg -> out cols 0..9
    k_gemm10<<<gN, 256, 0, stream>>>(S1, Wc, sF, N, 1);
    k_agg10_gather<<<gWave, 256, 0, stream>>>(out, sF, offs_m, csr_src_m, csr_w_m, inv_m, bc, N);

    // MLP chain, in-place on S1: t = relu(relu(a2)@M1+mb1); e3 = t@M2+mb2; v = e3@Wd
    k_gemm_mfma<<<gGemmM, 256, 0, stream>>>(S1, m1h, m1l, mb1, S1, N, 128, 1, 1, 0);
    k_gemm_mfma<<<gGemmM, 256, 0, stream>>>(S1, m2h, m2l, mb2, S1, N, 128, 0, 0, 0);
    k_gemm_mfma<<<gGemmM, 256, 0, stream>>>(S1, wdh, wdl, nullptr, S1, N, 128, 0, 0, 0);

    // scores -> out cols 10,11
    k_score<<<gScore, 256, 0, stream>>>(S1, S3, S2, out, N);
}